// Round 1
// baseline (826.273 us; speedup 1.0000x reference)
//
#include <hip/hip_runtime.h>

// ---------------------------------------------------------------------------
// FormulaNet GCN forward: 3x GCNConv(128) + mean-pool(512 graphs) + dense.
// Strategy: build CSR (by dst) per launch, gather-based aggregation (1 wave
// per node), fp32 register-tiled dense matmuls (no fp32 MFMA on CDNA4).
// norm fold: out[i] = dis[i]*(sum_e dis[s]*g[s] + dis[i]*g[i]) + b
// ---------------------------------------------------------------------------

__global__ void k_count(const int* __restrict__ dst, int* __restrict__ cnt, int E) {
    int e = blockIdx.x * 256 + threadIdx.x;
    if (e < E) atomicAdd(&cnt[dst[e]], 1);
}

// block-local exclusive scan over 256 ints; partial results + block sums
__global__ void k_scan1(const int* __restrict__ cnt, int* __restrict__ rp,
                        int* __restrict__ bsum, int n) {
    __shared__ int s[256];
    int i = blockIdx.x * 256 + threadIdx.x;
    int v = (i < n) ? cnt[i] : 0;
    s[threadIdx.x] = v;
    for (int off = 1; off < 256; off <<= 1) {
        __syncthreads();
        int t = (threadIdx.x >= off) ? s[threadIdx.x - off] : 0;
        __syncthreads();
        s[threadIdx.x] += t;
    }
    if (i < n) rp[i] = s[threadIdx.x] - v;          // exclusive within block
    if (threadIdx.x == 255) bsum[blockIdx.x] = s[255];
}

// scan the (<=512) block sums in one block
__global__ void k_scan2(int* __restrict__ bsum, int nb) {
    __shared__ int s[512];
    int v = (threadIdx.x < nb) ? bsum[threadIdx.x] : 0;
    s[threadIdx.x] = v;
    for (int off = 1; off < 512; off <<= 1) {
        __syncthreads();
        int t = (threadIdx.x >= off) ? s[threadIdx.x - off] : 0;
        __syncthreads();
        s[threadIdx.x] += t;
    }
    bsum[threadIdx.x] = s[threadIdx.x] - v;         // exclusive
}

__global__ void k_scan3(const int* __restrict__ cnt, const int* __restrict__ bsum,
                        int* __restrict__ rp, float* __restrict__ dis, int n, int E) {
    int i = blockIdx.x * 256 + threadIdx.x;
    if (i < n) {
        rp[i] += bsum[i >> 8];
        dis[i] = rsqrtf((float)(cnt[i] + 1));       // +1: self-loop; deg>=1 always
    } else if (i == n) {
        rp[n] = E;
    }
}

__global__ void k_fill(const int* __restrict__ src, const int* __restrict__ dst,
                       const int* __restrict__ rp, int* __restrict__ fill,
                       int* __restrict__ col, int E) {
    int e = blockIdx.x * 256 + threadIdx.x;
    if (e < E) {
        int d = dst[e];
        int pos = rp[d] + atomicAdd(&fill[d], 1);
        col[pos] = src[e];
    }
}

// h0 = relu(x @ W_d1 + b_d1) [N,4]; g = h0 @ W_g1 [N,128] (bias deferred)
__global__ __launch_bounds__(256) void k_layer1(
        const float* __restrict__ x, const float* __restrict__ Wd1,
        const float* __restrict__ bd1, const float* __restrict__ Wg1,
        float* __restrict__ g, int n) {
    __shared__ float sW[4 * 128];
    for (int t = threadIdx.x; t < 512; t += 256) sW[t] = Wg1[t];
    __syncthreads();
    int j = threadIdx.x & 127;
    int node = blockIdx.x * 2 + (threadIdx.x >> 7);
    if (node >= n) return;
    float4 xv = ((const float4*)x)[node];
    float acc = 0.f;
#pragma unroll
    for (int k = 0; k < 4; k++) {
        float h0 = xv.x * Wd1[k] + xv.y * Wd1[4 + k] + xv.z * Wd1[8 + k]
                 + xv.w * Wd1[12 + k] + bd1[k];
        h0 = fmaxf(h0, 0.f);
        acc = fmaf(h0, sW[k * 128 + j], acc);
    }
    g[(size_t)node * 128 + j] = acc;
}

// one wave per node; lane holds feats {2*lane, 2*lane+1} as float2
__global__ __launch_bounds__(256) void k_agg(
        const float* __restrict__ g, const int* __restrict__ rp,
        const int* __restrict__ col, const float* __restrict__ dis,
        const float* __restrict__ bias, float* __restrict__ h, int n) {
    int lane = threadIdx.x & 63;
    int node = __builtin_amdgcn_readfirstlane(blockIdx.x * 4 + (threadIdx.x >> 6));
    if (node >= n) return;
    int r0 = __builtin_amdgcn_readfirstlane(rp[node]);
    int r1 = __builtin_amdgcn_readfirstlane(rp[node + 1]);
    float di = dis[node];
    const float2* g2 = (const float2*)g;
    float2 me = g2[(size_t)node * 64 + lane];
    float ax = di * me.x, ay = di * me.y;   // self-loop term (dis_i factored out)
    int e = r0;
    for (; e + 1 < r1; e += 2) {
        int s0 = __builtin_amdgcn_readfirstlane(col[e]);
        int s1 = __builtin_amdgcn_readfirstlane(col[e + 1]);
        float w0 = dis[s0], w1 = dis[s1];
        float2 v0 = g2[(size_t)s0 * 64 + lane];
        float2 v1 = g2[(size_t)s1 * 64 + lane];
        ax = fmaf(w0, v0.x, ax); ay = fmaf(w0, v0.y, ay);
        ax = fmaf(w1, v1.x, ax); ay = fmaf(w1, v1.y, ay);
    }
    if (e < r1) {
        int s0 = __builtin_amdgcn_readfirstlane(col[e]);
        float w0 = dis[s0];
        float2 v0 = g2[(size_t)s0 * 64 + lane];
        ax = fmaf(w0, v0.x, ax); ay = fmaf(w0, v0.y, ay);
    }
    float2 b = ((const float2*)bias)[lane];
    float2 o;
    o.x = fmaxf(fmaf(di, ax, b.x), 0.f);
    o.y = fmaxf(fmaf(di, ay, b.y), 0.f);
    ((float2*)h)[(size_t)node * 64 + lane] = o;
}

// G[N,128] = H[N,128] @ W[128,128]; 32-row tile in LDS, 4x4 register blocking
__global__ __launch_bounds__(256) void k_mm128(
        const float* __restrict__ Hin, const float* __restrict__ W,
        float* __restrict__ Gout, int n) {
    __shared__ float sH[32 * 128];      // 16 KB
    int row0 = blockIdx.x * 32;
    int validRows = min(32, n - row0);
    const float4* H4 = (const float4*)(Hin + (size_t)row0 * 128);
    float4* sH4 = (float4*)sH;
    int lim = validRows * 32;
    for (int t = threadIdx.x; t < 1024; t += 256)
        if (t < lim) sH4[t] = H4[t];
    __syncthreads();
    int cg = threadIdx.x & 31;          // cols cg*4 .. cg*4+3
    int rg = threadIdx.x >> 5;          // rows rg*4 .. rg*4+3
    const float* h0 = sH + (rg * 4 + 0) * 128;
    const float* h1 = sH + (rg * 4 + 1) * 128;
    const float* h2 = sH + (rg * 4 + 2) * 128;
    const float* h3 = sH + (rg * 4 + 3) * 128;
    const float4* W4 = (const float4*)W;
    float4 acc0 = {0, 0, 0, 0}, acc1 = acc0, acc2 = acc0, acc3 = acc0;
#pragma unroll 8
    for (int k = 0; k < 128; k++) {
        float4 w = W4[k * 32 + cg];     // coalesced, L1-resident
        float a0 = h0[k], a1 = h1[k], a2 = h2[k], a3 = h3[k];  // 2-addr bcast, free
        acc0.x = fmaf(a0, w.x, acc0.x); acc0.y = fmaf(a0, w.y, acc0.y);
        acc0.z = fmaf(a0, w.z, acc0.z); acc0.w = fmaf(a0, w.w, acc0.w);
        acc1.x = fmaf(a1, w.x, acc1.x); acc1.y = fmaf(a1, w.y, acc1.y);
        acc1.z = fmaf(a1, w.z, acc1.z); acc1.w = fmaf(a1, w.w, acc1.w);
        acc2.x = fmaf(a2, w.x, acc2.x); acc2.y = fmaf(a2, w.y, acc2.y);
        acc2.z = fmaf(a2, w.z, acc2.z); acc2.w = fmaf(a2, w.w, acc2.w);
        acc3.x = fmaf(a3, w.x, acc3.x); acc3.y = fmaf(a3, w.y, acc3.y);
        acc3.z = fmaf(a3, w.z, acc3.z); acc3.w = fmaf(a3, w.w, acc3.w);
    }
    float4* out4 = (float4*)Gout;
    int r = rg * 4;
    if (row0 + r + 0 < n) out4[(size_t)(row0 + r + 0) * 32 + cg] = acc0;
    if (row0 + r + 1 < n) out4[(size_t)(row0 + r + 1) * 32 + cg] = acc1;
    if (row0 + r + 2 < n) out4[(size_t)(row0 + r + 2) * 32 + cg] = acc2;
    if (row0 + r + 3 < n) out4[(size_t)(row0 + r + 3) * 32 + cg] = acc3;
}

// batch is sorted: find per-graph node ranges (handles empty graphs)
__global__ void k_bounds(const int* __restrict__ batch, int* __restrict__ gs,
                         int n, int ng) {
    int i = blockIdx.x * 256 + threadIdx.x;
    if (i >= n) return;
    int b = batch[i];
    int prev = (i == 0) ? -1 : batch[i - 1];
    for (int g2 = prev + 1; g2 <= b; ++g2) gs[g2] = i;
    if (i == n - 1)
        for (int g2 = b + 1; g2 <= ng; ++g2) gs[g2] = n;
}

// fused mean-pool + final dense: one block (128 thr) per graph
__global__ __launch_bounds__(128) void k_pool(
        const float* __restrict__ h, const int* __restrict__ gs,
        const float* __restrict__ Wd2, const float* __restrict__ bd2,
        float* __restrict__ out, int n) {
    int gidx = blockIdx.x;
    int j = threadIdx.x;
    int s = gs[gidx], e2 = gs[gidx + 1];
    float acc = 0.f;
    for (int i = s; i < e2; ++i) acc += h[(size_t)i * 128 + j];
    float c = (float)((e2 - s) > 1 ? (e2 - s) : 1);
    __shared__ float sp[128];
    sp[j] = acc / c;
    __syncthreads();
    float o = bd2[j];
#pragma unroll 8
    for (int k = 0; k < 128; k++) o = fmaf(sp[k], Wd2[k * 128 + j], o);
    out[gidx * 128 + j] = o;
}

extern "C" void kernel_launch(void* const* d_in, const int* in_sizes, int n_in,
                              void* d_out, int out_size, void* d_ws, size_t ws_size,
                              hipStream_t stream) {
    const float* x   = (const float*)d_in[0];
    const int*  ei   = (const int*)d_in[1];
    const int* batch = (const int*)d_in[2];
    const float* Wd1 = (const float*)d_in[3];
    const float* bd1 = (const float*)d_in[4];
    const float* Wg1 = (const float*)d_in[5];
    const float* bg1 = (const float*)d_in[6];
    const float* Wg2 = (const float*)d_in[7];
    const float* bg2 = (const float*)d_in[8];
    const float* Wg3 = (const float*)d_in[9];
    const float* bg3 = (const float*)d_in[10];
    const float* Wd2 = (const float*)d_in[11];
    const float* bd2 = (const float*)d_in[12];
    float* out = (float*)d_out;

    int N  = in_sizes[0] / 4;       // N_FEAT = 4
    int E  = in_sizes[1] / 2;       // edge_index is [2, E]
    int NG = out_size / 128;        // 512 graphs
    const int* srcIdx = ei;
    const int* dstIdx = ei + E;

    char* p = (char*)d_ws;
    auto alloc = [&](size_t bytes) -> char* {
        char* r = p;
        p += (bytes + 255) & ~(size_t)255;
        return r;
    };
    int*   cnt  = (int*)alloc((size_t)N * 4);
    int*   fill = (int*)alloc((size_t)N * 4);
    int*   rp   = (int*)alloc(((size_t)N + 1) * 4);
    int*   bsum = (int*)alloc(512 * 4);
    float* dis  = (float*)alloc((size_t)N * 4);
    int*   col  = (int*)alloc((size_t)E * 4);
    int*   gs   = (int*)alloc(((size_t)NG + 1) * 4);
    float* g    = (float*)alloc((size_t)N * 128 * 4);
    float* h    = (float*)alloc((size_t)N * 128 * 4);
    (void)ws_size; (void)n_in;

    hipMemsetAsync(cnt, 0, (size_t)N * 4, stream);
    hipMemsetAsync(fill, 0, (size_t)N * 4, stream);

    int eb  = (E + 255) / 256;
    int nb1 = (N + 255) / 256;
    int sb3 = (N + 1 + 255) / 256;
    int ab  = (N + 3) / 4;
    int mb  = (N + 31) / 32;

    k_count<<<eb, 256, 0, stream>>>(dstIdx, cnt, E);
    k_scan1<<<nb1, 256, 0, stream>>>(cnt, rp, bsum, N);
    k_scan2<<<1, 512, 0, stream>>>(bsum, nb1);
    k_scan3<<<sb3, 256, 0, stream>>>(cnt, bsum, rp, dis, N, E);
    k_fill<<<eb, 256, 0, stream>>>(srcIdx, dstIdx, rp, fill, col, E);

    k_layer1<<<(N + 1) / 2, 256, 0, stream>>>(x, Wd1, bd1, Wg1, g, N);
    k_agg<<<ab, 256, 0, stream>>>(g, rp, col, dis, bg1, h, N);
    k_mm128<<<mb, 256, 0, stream>>>(h, Wg2, g, N);
    k_agg<<<ab, 256, 0, stream>>>(g, rp, col, dis, bg2, h, N);
    k_mm128<<<mb, 256, 0, stream>>>(h, Wg3, g, N);
    k_agg<<<ab, 256, 0, stream>>>(g, rp, col, dis, bg3, h, N);

    k_bounds<<<nb1, 256, 0, stream>>>(batch, gs, N, NG);
    k_pool<<<NG, 128, 0, stream>>>(h, gs, Wd2, bd2, out, N);
}

// Round 2
// 823.217 us; speedup vs baseline: 1.0037x; 1.0037x over previous
//
#include <hip/hip_runtime.h>

// ---------------------------------------------------------------------------
// FormulaNet GCN forward: 3x GCNConv(128) + mean-pool(512 graphs) + dense.
// CSR (by dst) built per launch; gather-based aggregation (1 wave per node);
// fp32 register-tiled dense matmuls (no fp32 MFMA on CDNA4).
// norm fold: out[i] = dis[i]*(sum_e dis[s]*g[s] + dis[i]*g[i]) + b
// R1: col packs src | (deg_in[src]<<17)  (N=100k < 2^17) so agg's per-edge
//     chain is col->gather only (dis recomputed via v_rsq_f32, bit-identical);
//     edge loop unrolled x4 with 4 gathers in flight; fill[] pre-seeded with
//     rp so k_fill does a single atomicAdd (no rp read, no fill memset).
// ---------------------------------------------------------------------------

__global__ void k_count(const int* __restrict__ dst, int* __restrict__ cnt, int E) {
    int e = blockIdx.x * 256 + threadIdx.x;
    if (e < E) atomicAdd(&cnt[dst[e]], 1);
}

// block-local exclusive scan over 256 ints; partial results + block sums
__global__ void k_scan1(const int* __restrict__ cnt, int* __restrict__ rp,
                        int* __restrict__ bsum, int n) {
    __shared__ int s[256];
    int i = blockIdx.x * 256 + threadIdx.x;
    int v = (i < n) ? cnt[i] : 0;
    s[threadIdx.x] = v;
    for (int off = 1; off < 256; off <<= 1) {
        __syncthreads();
        int t = (threadIdx.x >= off) ? s[threadIdx.x - off] : 0;
        __syncthreads();
        s[threadIdx.x] += t;
    }
    if (i < n) rp[i] = s[threadIdx.x] - v;          // exclusive within block
    if (threadIdx.x == 255) bsum[blockIdx.x] = s[255];
}

// scan the (<=512) block sums in one block
__global__ void k_scan2(int* __restrict__ bsum, int nb) {
    __shared__ int s[512];
    int v = (threadIdx.x < nb) ? bsum[threadIdx.x] : 0;
    s[threadIdx.x] = v;
    for (int off = 1; off < 512; off <<= 1) {
        __syncthreads();
        int t = (threadIdx.x >= off) ? s[threadIdx.x - off] : 0;
        __syncthreads();
        s[threadIdx.x] += t;
    }
    bsum[threadIdx.x] = s[threadIdx.x] - v;         // exclusive
}

__global__ void k_scan3(const int* __restrict__ cnt, const int* __restrict__ bsum,
                        int* __restrict__ rp, int* __restrict__ fill,
                        float* __restrict__ dis, int n, int E) {
    int i = blockIdx.x * 256 + threadIdx.x;
    if (i < n) {
        int v = rp[i] + bsum[i >> 8];
        rp[i] = v;
        fill[i] = v;                                // seed for k_fill atomics
        dis[i] = rsqrtf((float)(cnt[i] + 1));       // +1: self-loop
    } else if (i == n) {
        rp[n] = E;
    }
}

// col[pos] = src | (deg_in[src] << 17): one atomic, no rp read
__global__ void k_fill(const int* __restrict__ src, const int* __restrict__ dst,
                       const int* __restrict__ cnt, int* __restrict__ fill,
                       int* __restrict__ col, int E) {
    int e = blockIdx.x * 256 + threadIdx.x;
    if (e < E) {
        int d = dst[e];
        int s = src[e];
        int pos = atomicAdd(&fill[d], 1);
        col[pos] = s | (cnt[s] << 17);
    }
}

// h0 = relu(x @ W_d1 + b_d1) [N,4]; g = h0 @ W_g1 [N,128] (bias deferred)
__global__ __launch_bounds__(256) void k_layer1(
        const float* __restrict__ x, const float* __restrict__ Wd1,
        const float* __restrict__ bd1, const float* __restrict__ Wg1,
        float* __restrict__ g, int n) {
    __shared__ float sW[4 * 128];
    for (int t = threadIdx.x; t < 512; t += 256) sW[t] = Wg1[t];
    __syncthreads();
    int j = threadIdx.x & 127;
    int node = blockIdx.x * 2 + (threadIdx.x >> 7);
    if (node >= n) return;
    float4 xv = ((const float4*)x)[node];
    float acc = 0.f;
#pragma unroll
    for (int k = 0; k < 4; k++) {
        float h0 = xv.x * Wd1[k] + xv.y * Wd1[4 + k] + xv.z * Wd1[8 + k]
                 + xv.w * Wd1[12 + k] + bd1[k];
        h0 = fmaxf(h0, 0.f);
        acc = fmaf(h0, sW[k * 128 + j], acc);
    }
    g[(size_t)node * 128 + j] = acc;
}

__device__ __forceinline__ void agg_edge_decode(int c, int& s, float& w) {
    s = c & 0x1FFFF;
    w = rsqrtf((float)((unsigned)c >> 17) + 1.0f);
}

// one wave per node; lane holds feats {2*lane, 2*lane+1} as float2
__global__ __launch_bounds__(256) void k_agg(
        const float* __restrict__ g, const int* __restrict__ rp,
        const int* __restrict__ col, const float* __restrict__ dis,
        const float* __restrict__ bias, float* __restrict__ h, int n) {
    int lane = threadIdx.x & 63;
    int node = __builtin_amdgcn_readfirstlane(blockIdx.x * 4 + (threadIdx.x >> 6));
    if (node >= n) return;
    int r0 = __builtin_amdgcn_readfirstlane(rp[node]);
    int r1 = __builtin_amdgcn_readfirstlane(rp[node + 1]);
    float di = dis[node];
    const float2* g2 = (const float2*)g;
    float2 me = g2[(size_t)node * 64 + lane];
    float ax = di * me.x, ay = di * me.y;   // self-loop term (dis_i factored out)
    int e = r0;
    for (; e + 3 < r1; e += 4) {
        int c0 = __builtin_amdgcn_readfirstlane(col[e]);
        int c1 = __builtin_amdgcn_readfirstlane(col[e + 1]);
        int c2 = __builtin_amdgcn_readfirstlane(col[e + 2]);
        int c3 = __builtin_amdgcn_readfirstlane(col[e + 3]);
        int s0, s1, s2, s3; float w0, w1, w2, w3;
        agg_edge_decode(c0, s0, w0); agg_edge_decode(c1, s1, w1);
        agg_edge_decode(c2, s2, w2); agg_edge_decode(c3, s3, w3);
        float2 v0 = g2[(size_t)s0 * 64 + lane];
        float2 v1 = g2[(size_t)s1 * 64 + lane];
        float2 v2 = g2[(size_t)s2 * 64 + lane];
        float2 v3 = g2[(size_t)s3 * 64 + lane];
        ax = fmaf(w0, v0.x, ax); ay = fmaf(w0, v0.y, ay);
        ax = fmaf(w1, v1.x, ax); ay = fmaf(w1, v1.y, ay);
        ax = fmaf(w2, v2.x, ax); ay = fmaf(w2, v2.y, ay);
        ax = fmaf(w3, v3.x, ax); ay = fmaf(w3, v3.y, ay);
    }
    for (; e < r1; ++e) {
        int c0 = __builtin_amdgcn_readfirstlane(col[e]);
        int s0; float w0;
        agg_edge_decode(c0, s0, w0);
        float2 v0 = g2[(size_t)s0 * 64 + lane];
        ax = fmaf(w0, v0.x, ax); ay = fmaf(w0, v0.y, ay);
    }
    float2 b = ((const float2*)bias)[lane];
    float2 o;
    o.x = fmaxf(fmaf(di, ax, b.x), 0.f);
    o.y = fmaxf(fmaf(di, ay, b.y), 0.f);
    ((float2*)h)[(size_t)node * 64 + lane] = o;
}

// G[N,128] = H[N,128] @ W[128,128]; 32-row tile in LDS, 4x4 register blocking
__global__ __launch_bounds__(256) void k_mm128(
        const float* __restrict__ Hin, const float* __restrict__ W,
        float* __restrict__ Gout, int n) {
    __shared__ float sH[32 * 128];      // 16 KB
    int row0 = blockIdx.x * 32;
    int validRows = min(32, n - row0);
    const float4* H4 = (const float4*)(Hin + (size_t)row0 * 128);
    float4* sH4 = (float4*)sH;
    int lim = validRows * 32;
    for (int t = threadIdx.x; t < 1024; t += 256)
        if (t < lim) sH4[t] = H4[t];
    __syncthreads();
    int cg = threadIdx.x & 31;          // cols cg*4 .. cg*4+3
    int rg = threadIdx.x >> 5;          // rows rg*4 .. rg*4+3
    const float* h0 = sH + (rg * 4 + 0) * 128;
    const float* h1 = sH + (rg * 4 + 1) * 128;
    const float* h2 = sH + (rg * 4 + 2) * 128;
    const float* h3 = sH + (rg * 4 + 3) * 128;
    const float4* W4 = (const float4*)W;
    float4 acc0 = {0, 0, 0, 0}, acc1 = acc0, acc2 = acc0, acc3 = acc0;
#pragma unroll 8
    for (int k = 0; k < 128; k++) {
        float4 w = W4[k * 32 + cg];     // coalesced, L1/L2-resident
        float a0 = h0[k], a1 = h1[k], a2 = h2[k], a3 = h3[k];  // LDS broadcast
        acc0.x = fmaf(a0, w.x, acc0.x); acc0.y = fmaf(a0, w.y, acc0.y);
        acc0.z = fmaf(a0, w.z, acc0.z); acc0.w = fmaf(a0, w.w, acc0.w);
        acc1.x = fmaf(a1, w.x, acc1.x); acc1.y = fmaf(a1, w.y, acc1.y);
        acc1.z = fmaf(a1, w.z, acc1.z); acc1.w = fmaf(a1, w.w, acc1.w);
        acc2.x = fmaf(a2, w.x, acc2.x); acc2.y = fmaf(a2, w.y, acc2.y);
        acc2.z = fmaf(a2, w.z, acc2.z); acc2.w = fmaf(a2, w.w, acc2.w);
        acc3.x = fmaf(a3, w.x, acc3.x); acc3.y = fmaf(a3, w.y, acc3.y);
        acc3.z = fmaf(a3, w.z, acc3.z); acc3.w = fmaf(a3, w.w, acc3.w);
    }
    float4* out4 = (float4*)Gout;
    int r = rg * 4;
    if (row0 + r + 0 < n) out4[(size_t)(row0 + r + 0) * 32 + cg] = acc0;
    if (row0 + r + 1 < n) out4[(size_t)(row0 + r + 1) * 32 + cg] = acc1;
    if (row0 + r + 2 < n) out4[(size_t)(row0 + r + 2) * 32 + cg] = acc2;
    if (row0 + r + 3 < n) out4[(size_t)(row0 + r + 3) * 32 + cg] = acc3;
}

// batch is sorted: find per-graph node ranges (handles empty graphs)
__global__ void k_bounds(const int* __restrict__ batch, int* __restrict__ gs,
                         int n, int ng) {
    int i = blockIdx.x * 256 + threadIdx.x;
    if (i >= n) return;
    int b = batch[i];
    int prev = (i == 0) ? -1 : batch[i - 1];
    for (int g2 = prev + 1; g2 <= b; ++g2) gs[g2] = i;
    if (i == n - 1)
        for (int g2 = b + 1; g2 <= ng; ++g2) gs[g2] = n;
}

// fused mean-pool + final dense: one block (128 thr) per graph
__global__ __launch_bounds__(128) void k_pool(
        const float* __restrict__ h, const int* __restrict__ gs,
        const float* __restrict__ Wd2, const float* __restrict__ bd2,
        float* __restrict__ out, int n) {
    int gidx = blockIdx.x;
    int j = threadIdx.x;
    int s = gs[gidx], e2 = gs[gidx + 1];
    float acc = 0.f;
    for (int i = s; i < e2; ++i) acc += h[(size_t)i * 128 + j];
    float c = (float)((e2 - s) > 1 ? (e2 - s) : 1);
    __shared__ float sp[128];
    sp[j] = acc / c;
    __syncthreads();
    float o = bd2[j];
#pragma unroll 8
    for (int k = 0; k < 128; k++) o = fmaf(sp[k], Wd2[k * 128 + j], o);
    out[gidx * 128 + j] = o;
}

extern "C" void kernel_launch(void* const* d_in, const int* in_sizes, int n_in,
                              void* d_out, int out_size, void* d_ws, size_t ws_size,
                              hipStream_t stream) {
    const float* x   = (const float*)d_in[0];
    const int*  ei   = (const int*)d_in[1];
    const int* batch = (const int*)d_in[2];
    const float* Wd1 = (const float*)d_in[3];
    const float* bd1 = (const float*)d_in[4];
    const float* Wg1 = (const float*)d_in[5];
    const float* bg1 = (const float*)d_in[6];
    const float* Wg2 = (const float*)d_in[7];
    const float* bg2 = (const float*)d_in[8];
    const float* Wg3 = (const float*)d_in[9];
    const float* bg3 = (const float*)d_in[10];
    const float* Wd2 = (const float*)d_in[11];
    const float* bd2 = (const float*)d_in[12];
    float* out = (float*)d_out;

    int N  = in_sizes[0] / 4;       // N_FEAT = 4
    int E  = in_sizes[1] / 2;       // edge_index is [2, E]
    int NG = out_size / 128;        // 512 graphs
    const int* srcIdx = ei;
    const int* dstIdx = ei + E;

    char* p = (char*)d_ws;
    auto alloc = [&](size_t bytes) -> char* {
        char* r = p;
        p += (bytes + 255) & ~(size_t)255;
        return r;
    };
    int*   cnt  = (int*)alloc((size_t)N * 4);
    int*   fill = (int*)alloc((size_t)N * 4);
    int*   rp   = (int*)alloc(((size_t)N + 1) * 4);
    int*   bsum = (int*)alloc(512 * 4);
    float* dis  = (float*)alloc((size_t)N * 4);
    int*   col  = (int*)alloc((size_t)E * 4);
    int*   gs   = (int*)alloc(((size_t)NG + 1) * 4);
    float* g    = (float*)alloc((size_t)N * 128 * 4);
    float* h    = (float*)alloc((size_t)N * 128 * 4);
    (void)ws_size; (void)n_in;

    hipMemsetAsync(cnt, 0, (size_t)N * 4, stream);

    int eb  = (E + 255) / 256;
    int nb1 = (N + 255) / 256;
    int sb3 = (N + 1 + 255) / 256;
    int ab  = (N + 3) / 4;
    int mb  = (N + 31) / 32;

    k_count<<<eb, 256, 0, stream>>>(dstIdx, cnt, E);
    k_scan1<<<nb1, 256, 0, stream>>>(cnt, rp, bsum, N);
    k_scan2<<<1, 512, 0, stream>>>(bsum, nb1);
    k_scan3<<<sb3, 256, 0, stream>>>(cnt, bsum, rp, fill, dis, N, E);
    k_fill<<<eb, 256, 0, stream>>>(srcIdx, dstIdx, cnt, fill, col, E);

    k_layer1<<<(N + 1) / 2, 256, 0, stream>>>(x, Wd1, bd1, Wg1, g, N);
    k_agg<<<ab, 256, 0, stream>>>(g, rp, col, dis, bg1, h, N);
    k_mm128<<<mb, 256, 0, stream>>>(h, Wg2, g, N);
    k_agg<<<ab, 256, 0, stream>>>(g, rp, col, dis, bg2, h, N);
    k_mm128<<<mb, 256, 0, stream>>>(h, Wg3, g, N);
    k_agg<<<ab, 256, 0, stream>>>(g, rp, col, dis, bg3, h, N);

    k_bounds<<<nb1, 256, 0, stream>>>(batch, gs, N, NG);
    k_pool<<<NG, 128, 0, stream>>>(h, gs, Wd2, bd2, out, N);
}

// Round 3
// 655.379 us; speedup vs baseline: 1.2608x; 1.2561x over previous
//
#include <hip/hip_runtime.h>
#include <hip/hip_fp16.h>

// ---------------------------------------------------------------------------
// FormulaNet GCN forward: 3x GCNConv(128) + mean-pool(512 graphs) + dense.
// CSR (by dst) built per launch; gather-based aggregation (1 wave per node);
// fp32 register-tiled dense matmuls (no fp32 MFMA on CDNA4).
// norm fold: out[i] = dis[i]*(sum_e dis[s]*g[s] + dis[i]*g[i]) + b
// R1: col packs src | (deg_in[src]<<17); agg chain is col->gather only.
// R2: intermediate node tensors g,h stored fp16 (fp32 math/accum) — halves
//     the random-gather traffic that bounds k_agg (~4 TB/s path ceiling,
//     50% L2 hit is structural for a random graph: ~16 reqs/line over 8 XCDs).
// ---------------------------------------------------------------------------

__global__ void k_count(const int* __restrict__ dst, int* __restrict__ cnt, int E) {
    int e = blockIdx.x * 256 + threadIdx.x;
    if (e < E) atomicAdd(&cnt[dst[e]], 1);
}

// block-local exclusive scan over 256 ints; partial results + block sums
__global__ void k_scan1(const int* __restrict__ cnt, int* __restrict__ rp,
                        int* __restrict__ bsum, int n) {
    __shared__ int s[256];
    int i = blockIdx.x * 256 + threadIdx.x;
    int v = (i < n) ? cnt[i] : 0;
    s[threadIdx.x] = v;
    for (int off = 1; off < 256; off <<= 1) {
        __syncthreads();
        int t = (threadIdx.x >= off) ? s[threadIdx.x - off] : 0;
        __syncthreads();
        s[threadIdx.x] += t;
    }
    if (i < n) rp[i] = s[threadIdx.x] - v;          // exclusive within block
    if (threadIdx.x == 255) bsum[blockIdx.x] = s[255];
}

// scan the (<=512) block sums in one block
__global__ void k_scan2(int* __restrict__ bsum, int nb) {
    __shared__ int s[512];
    int v = (threadIdx.x < nb) ? bsum[threadIdx.x] : 0;
    s[threadIdx.x] = v;
    for (int off = 1; off < 512; off <<= 1) {
        __syncthreads();
        int t = (threadIdx.x >= off) ? s[threadIdx.x - off] : 0;
        __syncthreads();
        s[threadIdx.x] += t;
    }
    bsum[threadIdx.x] = s[threadIdx.x] - v;         // exclusive
}

__global__ void k_scan3(const int* __restrict__ cnt, const int* __restrict__ bsum,
                        int* __restrict__ rp, int* __restrict__ fill,
                        float* __restrict__ dis, int n, int E) {
    int i = blockIdx.x * 256 + threadIdx.x;
    if (i < n) {
        int v = rp[i] + bsum[i >> 8];
        rp[i] = v;
        fill[i] = v;                                // seed for k_fill atomics
        dis[i] = rsqrtf((float)(cnt[i] + 1));       // +1: self-loop
    } else if (i == n) {
        rp[n] = E;
    }
}

// col[pos] = src | (deg_in[src] << 17): one atomic, no rp read
__global__ void k_fill(const int* __restrict__ src, const int* __restrict__ dst,
                       const int* __restrict__ cnt, int* __restrict__ fill,
                       int* __restrict__ col, int E) {
    int e = blockIdx.x * 256 + threadIdx.x;
    if (e < E) {
        int d = dst[e];
        int s = src[e];
        int pos = atomicAdd(&fill[d], 1);
        col[pos] = s | (cnt[s] << 17);
    }
}

// h0 = relu(x @ W_d1 + b_d1) [N,4]; g = h0 @ W_g1 [N,128] fp16 (bias deferred)
__global__ __launch_bounds__(256) void k_layer1(
        const float* __restrict__ x, const float* __restrict__ Wd1,
        const float* __restrict__ bd1, const float* __restrict__ Wg1,
        __half* __restrict__ g, int n) {
    __shared__ float sW[4 * 128];
    for (int t = threadIdx.x; t < 512; t += 256) sW[t] = Wg1[t];
    __syncthreads();
    int j = threadIdx.x & 127;
    int node = blockIdx.x * 2 + (threadIdx.x >> 7);
    if (node >= n) return;
    float4 xv = ((const float4*)x)[node];
    float acc = 0.f;
#pragma unroll
    for (int k = 0; k < 4; k++) {
        float h0 = xv.x * Wd1[k] + xv.y * Wd1[4 + k] + xv.z * Wd1[8 + k]
                 + xv.w * Wd1[12 + k] + bd1[k];
        h0 = fmaxf(h0, 0.f);
        acc = fmaf(h0, sW[k * 128 + j], acc);
    }
    g[(size_t)node * 128 + j] = __float2half_rn(acc);
}

__device__ __forceinline__ void agg_edge_decode(int c, int& s, float& w) {
    s = c & 0x1FFFF;
    w = rsqrtf((float)((unsigned)c >> 17) + 1.0f);
}

// one wave per node; lane holds feats {2*lane, 2*lane+1} as __half2 (4 B/lane)
__global__ __launch_bounds__(256) void k_agg(
        const __half* __restrict__ g, const int* __restrict__ rp,
        const int* __restrict__ col, const float* __restrict__ dis,
        const float* __restrict__ bias, __half* __restrict__ h, int n) {
    int lane = threadIdx.x & 63;
    int node = __builtin_amdgcn_readfirstlane(blockIdx.x * 4 + (threadIdx.x >> 6));
    if (node >= n) return;
    int r0 = __builtin_amdgcn_readfirstlane(rp[node]);
    int r1 = __builtin_amdgcn_readfirstlane(rp[node + 1]);
    float di = dis[node];
    const __half2* g2 = (const __half2*)g;
    float2 me = __half22float2(g2[(size_t)node * 64 + lane]);
    float ax = di * me.x, ay = di * me.y;   // self-loop term (dis_i factored out)
    int e = r0;
    for (; e + 3 < r1; e += 4) {
        int c0 = __builtin_amdgcn_readfirstlane(col[e]);
        int c1 = __builtin_amdgcn_readfirstlane(col[e + 1]);
        int c2 = __builtin_amdgcn_readfirstlane(col[e + 2]);
        int c3 = __builtin_amdgcn_readfirstlane(col[e + 3]);
        int s0, s1, s2, s3; float w0, w1, w2, w3;
        agg_edge_decode(c0, s0, w0); agg_edge_decode(c1, s1, w1);
        agg_edge_decode(c2, s2, w2); agg_edge_decode(c3, s3, w3);
        float2 v0 = __half22float2(g2[(size_t)s0 * 64 + lane]);
        float2 v1 = __half22float2(g2[(size_t)s1 * 64 + lane]);
        float2 v2 = __half22float2(g2[(size_t)s2 * 64 + lane]);
        float2 v3 = __half22float2(g2[(size_t)s3 * 64 + lane]);
        ax = fmaf(w0, v0.x, ax); ay = fmaf(w0, v0.y, ay);
        ax = fmaf(w1, v1.x, ax); ay = fmaf(w1, v1.y, ay);
        ax = fmaf(w2, v2.x, ax); ay = fmaf(w2, v2.y, ay);
        ax = fmaf(w3, v3.x, ax); ay = fmaf(w3, v3.y, ay);
    }
    for (; e < r1; ++e) {
        int c0 = __builtin_amdgcn_readfirstlane(col[e]);
        int s0; float w0;
        agg_edge_decode(c0, s0, w0);
        float2 v0 = __half22float2(g2[(size_t)s0 * 64 + lane]);
        ax = fmaf(w0, v0.x, ax); ay = fmaf(w0, v0.y, ay);
    }
    float2 b = ((const float2*)bias)[lane];
    float ox = fmaxf(fmaf(di, ax, b.x), 0.f);
    float oy = fmaxf(fmaf(di, ay, b.y), 0.f);
    ((__half2*)h)[(size_t)node * 64 + lane] = __floats2half2_rn(ox, oy);
}

// G[N,128] = H[N,128] @ W[128,128]; H fp16 in, G fp16 out, fp32 math.
// 32-row tile in LDS (fp32), 4x4 register blocking.
__global__ __launch_bounds__(256) void k_mm128(
        const __half* __restrict__ Hin, const float* __restrict__ W,
        __half* __restrict__ Gout, int n) {
    __shared__ float sH[32 * 128];      // 16 KB
    int row0 = blockIdx.x * 32;
    int validRows = min(32, n - row0);
    const __half2* H2 = (const __half2*)(Hin + (size_t)row0 * 128);
    float2* sH2 = (float2*)sH;
    int lim = validRows * 64;           // half2 count
    for (int t = threadIdx.x; t < 2048; t += 256)
        if (t < lim) sH2[t] = __half22float2(H2[t]);
    __syncthreads();
    int cg = threadIdx.x & 31;          // cols cg*4 .. cg*4+3
    int rg = threadIdx.x >> 5;          // rows rg*4 .. rg*4+3
    const float* h0 = sH + (rg * 4 + 0) * 128;
    const float* h1 = sH + (rg * 4 + 1) * 128;
    const float* h2 = sH + (rg * 4 + 2) * 128;
    const float* h3 = sH + (rg * 4 + 3) * 128;
    const float4* W4 = (const float4*)W;
    float4 acc0 = {0, 0, 0, 0}, acc1 = acc0, acc2 = acc0, acc3 = acc0;
#pragma unroll 8
    for (int k = 0; k < 128; k++) {
        float4 w = W4[k * 32 + cg];     // coalesced, L1/L2-resident
        float a0 = h0[k], a1 = h1[k], a2 = h2[k], a3 = h3[k];  // LDS broadcast
        acc0.x = fmaf(a0, w.x, acc0.x); acc0.y = fmaf(a0, w.y, acc0.y);
        acc0.z = fmaf(a0, w.z, acc0.z); acc0.w = fmaf(a0, w.w, acc0.w);
        acc1.x = fmaf(a1, w.x, acc1.x); acc1.y = fmaf(a1, w.y, acc1.y);
        acc1.z = fmaf(a1, w.z, acc1.z); acc1.w = fmaf(a1, w.w, acc1.w);
        acc2.x = fmaf(a2, w.x, acc2.x); acc2.y = fmaf(a2, w.y, acc2.y);
        acc2.z = fmaf(a2, w.z, acc2.z); acc2.w = fmaf(a2, w.w, acc2.w);
        acc3.x = fmaf(a3, w.x, acc3.x); acc3.y = fmaf(a3, w.y, acc3.y);
        acc3.z = fmaf(a3, w.z, acc3.z); acc3.w = fmaf(a3, w.w, acc3.w);
    }
    union { __half2 h2v[2]; uint2 u; } pk;
    int r = rg * 4;
#pragma unroll
    for (int i = 0; i < 4; i++) {
        if (row0 + r + i < n) {
            float4 a = (i == 0) ? acc0 : (i == 1) ? acc1 : (i == 2) ? acc2 : acc3;
            pk.h2v[0] = __floats2half2_rn(a.x, a.y);
            pk.h2v[1] = __floats2half2_rn(a.z, a.w);
            *(uint2*)(Gout + (size_t)(row0 + r + i) * 128 + cg * 4) = pk.u;
        }
    }
}

// batch is sorted: find per-graph node ranges (handles empty graphs)
__global__ void k_bounds(const int* __restrict__ batch, int* __restrict__ gs,
                         int n, int ng) {
    int i = blockIdx.x * 256 + threadIdx.x;
    if (i >= n) return;
    int b = batch[i];
    int prev = (i == 0) ? -1 : batch[i - 1];
    for (int g2 = prev + 1; g2 <= b; ++g2) gs[g2] = i;
    if (i == n - 1)
        for (int g2 = b + 1; g2 <= ng; ++g2) gs[g2] = n;
}

// fused mean-pool + final dense: one block (128 thr) per graph; out fp32
__global__ __launch_bounds__(128) void k_pool(
        const __half* __restrict__ h, const int* __restrict__ gs,
        const float* __restrict__ Wd2, const float* __restrict__ bd2,
        float* __restrict__ out, int n) {
    int gidx = blockIdx.x;
    int j = threadIdx.x;
    int s = gs[gidx], e2 = gs[gidx + 1];
    float acc = 0.f;
    for (int i = s; i < e2; ++i) acc += __half2float(h[(size_t)i * 128 + j]);
    float c = (float)((e2 - s) > 1 ? (e2 - s) : 1);
    __shared__ float sp[128];
    sp[j] = acc / c;
    __syncthreads();
    float o = bd2[j];
#pragma unroll 8
    for (int k = 0; k < 128; k++) o = fmaf(sp[k], Wd2[k * 128 + j], o);
    out[gidx * 128 + j] = o;
}

extern "C" void kernel_launch(void* const* d_in, const int* in_sizes, int n_in,
                              void* d_out, int out_size, void* d_ws, size_t ws_size,
                              hipStream_t stream) {
    const float* x   = (const float*)d_in[0];
    const int*  ei   = (const int*)d_in[1];
    const int* batch = (const int*)d_in[2];
    const float* Wd1 = (const float*)d_in[3];
    const float* bd1 = (const float*)d_in[4];
    const float* Wg1 = (const float*)d_in[5];
    const float* bg1 = (const float*)d_in[6];
    const float* Wg2 = (const float*)d_in[7];
    const float* bg2 = (const float*)d_in[8];
    const float* Wg3 = (const float*)d_in[9];
    const float* bg3 = (const float*)d_in[10];
    const float* Wd2 = (const float*)d_in[11];
    const float* bd2 = (const float*)d_in[12];
    float* out = (float*)d_out;

    int N  = in_sizes[0] / 4;       // N_FEAT = 4
    int E  = in_sizes[1] / 2;       // edge_index is [2, E]
    int NG = out_size / 128;        // 512 graphs
    const int* srcIdx = ei;
    const int* dstIdx = ei + E;

    char* p = (char*)d_ws;
    auto alloc = [&](size_t bytes) -> char* {
        char* r = p;
        p += (bytes + 255) & ~(size_t)255;
        return r;
    };
    int*    cnt  = (int*)alloc((size_t)N * 4);
    int*    fill = (int*)alloc((size_t)N * 4);
    int*    rp   = (int*)alloc(((size_t)N + 1) * 4);
    int*    bsum = (int*)alloc(512 * 4);
    float*  dis  = (float*)alloc((size_t)N * 4);
    int*    col  = (int*)alloc((size_t)E * 4);
    int*    gs   = (int*)alloc(((size_t)NG + 1) * 4);
    __half* g    = (__half*)alloc((size_t)N * 128 * 2);
    __half* h    = (__half*)alloc((size_t)N * 128 * 2);
    (void)ws_size; (void)n_in;

    hipMemsetAsync(cnt, 0, (size_t)N * 4, stream);

    int eb  = (E + 255) / 256;
    int nb1 = (N + 255) / 256;
    int sb3 = (N + 1 + 255) / 256;
    int ab  = (N + 3) / 4;
    int mb  = (N + 31) / 32;

    k_count<<<eb, 256, 0, stream>>>(dstIdx, cnt, E);
    k_scan1<<<nb1, 256, 0, stream>>>(cnt, rp, bsum, N);
    k_scan2<<<1, 512, 0, stream>>>(bsum, nb1);
    k_scan3<<<sb3, 256, 0, stream>>>(cnt, bsum, rp, fill, dis, N, E);
    k_fill<<<eb, 256, 0, stream>>>(srcIdx, dstIdx, cnt, fill, col, E);

    k_layer1<<<(N + 1) / 2, 256, 0, stream>>>(x, Wd1, bd1, Wg1, g, N);
    k_agg<<<ab, 256, 0, stream>>>(g, rp, col, dis, bg1, h, N);
    k_mm128<<<mb, 256, 0, stream>>>(h, Wg2, g, N);
    k_agg<<<ab, 256, 0, stream>>>(g, rp, col, dis, bg2, h, N);
    k_mm128<<<mb, 256, 0, stream>>>(h, Wg3, g, N);
    k_agg<<<ab, 256, 0, stream>>>(g, rp, col, dis, bg3, h, N);

    k_bounds<<<nb1, 256, 0, stream>>>(batch, gs, N, NG);
    k_pool<<<NG, 128, 0, stream>>>(h, gs, Wd2, bd2, out, N);
}

// Round 4
// 650.592 us; speedup vs baseline: 1.2700x; 1.0074x over previous
//
#include <hip/hip_runtime.h>
#include <hip/hip_fp16.h>

// ---------------------------------------------------------------------------
// FormulaNet GCN forward: 3x GCNConv(128) + mean-pool(512 graphs) + dense.
// CSR (by dst) built per launch; gather-based aggregation (1 wave per node);
// fp32 register-tiled dense matmuls (no fp32 MFMA on CDNA4).
// norm fold: out[i] = dis[i]*(sum_e dis[s]*g[s] + dis[i]*g[i]) + b
// R1: col packs src | (deg_in[src]<<17); agg chain is col->gather only.
// R2: intermediate node tensors g,h stored fp16 (fp32 math/accum) — halves
//     the random-gather traffic that bounds k_agg. [WIN: agg 121->~62 us]
// R3: cnt/fill atomic arrays padded to 1 counter / 128B line (stride 32):
//     512 serialized atomics/line -> 16. Compact cntc[] copy for k_fill's
//     random deg read so it stays L2-resident.
// ---------------------------------------------------------------------------

#define CPAD 32   // counter stride in ints: one counter per 128 B line

__global__ void k_count(const int* __restrict__ dst, int* __restrict__ cnt, int E) {
    int e = blockIdx.x * 256 + threadIdx.x;
    if (e < E) atomicAdd(&cnt[(size_t)dst[e] * CPAD], 1);
}

// block-local exclusive scan over 256 ints (strided source); partials + sums
__global__ void k_scan1(const int* __restrict__ cnt, int* __restrict__ rp,
                        int* __restrict__ bsum, int n) {
    __shared__ int s[256];
    int i = blockIdx.x * 256 + threadIdx.x;
    int v = (i < n) ? cnt[(size_t)i * CPAD] : 0;
    s[threadIdx.x] = v;
    for (int off = 1; off < 256; off <<= 1) {
        __syncthreads();
        int t = (threadIdx.x >= off) ? s[threadIdx.x - off] : 0;
        __syncthreads();
        s[threadIdx.x] += t;
    }
    if (i < n) rp[i] = s[threadIdx.x] - v;          // exclusive within block
    if (threadIdx.x == 255) bsum[blockIdx.x] = s[255];
}

// scan the (<=512) block sums in one block
__global__ void k_scan2(int* __restrict__ bsum, int nb) {
    __shared__ int s[512];
    int v = (threadIdx.x < nb) ? bsum[threadIdx.x] : 0;
    s[threadIdx.x] = v;
    for (int off = 1; off < 512; off <<= 1) {
        __syncthreads();
        int t = (threadIdx.x >= off) ? s[threadIdx.x - off] : 0;
        __syncthreads();
        s[threadIdx.x] += t;
    }
    bsum[threadIdx.x] = s[threadIdx.x] - v;         // exclusive
}

__global__ void k_scan3(const int* __restrict__ cnt, const int* __restrict__ bsum,
                        int* __restrict__ rp, int* __restrict__ fill,
                        int* __restrict__ cntc, float* __restrict__ dis,
                        int n, int E) {
    int i = blockIdx.x * 256 + threadIdx.x;
    if (i < n) {
        int c = cnt[(size_t)i * CPAD];
        int v = rp[i] + bsum[i >> 8];
        rp[i] = v;
        fill[(size_t)i * CPAD] = v;                 // seed for k_fill atomics
        cntc[i] = c;                                // compact deg for k_fill read
        dis[i] = rsqrtf((float)(c + 1));            // +1: self-loop
    } else if (i == n) {
        rp[n] = E;
    }
}

// col[pos] = src | (deg_in[src] << 17): one padded atomic, compact deg read
__global__ void k_fill(const int* __restrict__ src, const int* __restrict__ dst,
                       const int* __restrict__ cntc, int* __restrict__ fill,
                       int* __restrict__ col, int E) {
    int e = blockIdx.x * 256 + threadIdx.x;
    if (e < E) {
        int d = dst[e];
        int s = src[e];
        int pos = atomicAdd(&fill[(size_t)d * CPAD], 1);
        col[pos] = s | (cntc[s] << 17);
    }
}

// h0 = relu(x @ W_d1 + b_d1) [N,4]; g = h0 @ W_g1 [N,128] fp16 (bias deferred)
__global__ __launch_bounds__(256) void k_layer1(
        const float* __restrict__ x, const float* __restrict__ Wd1,
        const float* __restrict__ bd1, const float* __restrict__ Wg1,
        __half* __restrict__ g, int n) {
    __shared__ float sW[4 * 128];
    for (int t = threadIdx.x; t < 512; t += 256) sW[t] = Wg1[t];
    __syncthreads();
    int j = threadIdx.x & 127;
    int node = blockIdx.x * 2 + (threadIdx.x >> 7);
    if (node >= n) return;
    float4 xv = ((const float4*)x)[node];
    float acc = 0.f;
#pragma unroll
    for (int k = 0; k < 4; k++) {
        float h0 = xv.x * Wd1[k] + xv.y * Wd1[4 + k] + xv.z * Wd1[8 + k]
                 + xv.w * Wd1[12 + k] + bd1[k];
        h0 = fmaxf(h0, 0.f);
        acc = fmaf(h0, sW[k * 128 + j], acc);
    }
    g[(size_t)node * 128 + j] = __float2half_rn(acc);
}

__device__ __forceinline__ void agg_edge_decode(int c, int& s, float& w) {
    s = c & 0x1FFFF;
    w = rsqrtf((float)((unsigned)c >> 17) + 1.0f);
}

// one wave per node; lane holds feats {2*lane, 2*lane+1} as __half2 (4 B/lane)
__global__ __launch_bounds__(256) void k_agg(
        const __half* __restrict__ g, const int* __restrict__ rp,
        const int* __restrict__ col, const float* __restrict__ dis,
        const float* __restrict__ bias, __half* __restrict__ h, int n) {
    int lane = threadIdx.x & 63;
    int node = __builtin_amdgcn_readfirstlane(blockIdx.x * 4 + (threadIdx.x >> 6));
    if (node >= n) return;
    int r0 = __builtin_amdgcn_readfirstlane(rp[node]);
    int r1 = __builtin_amdgcn_readfirstlane(rp[node + 1]);
    float di = dis[node];
    const __half2* g2 = (const __half2*)g;
    float2 me = __half22float2(g2[(size_t)node * 64 + lane]);
    float ax = di * me.x, ay = di * me.y;   // self-loop term (dis_i factored out)
    int e = r0;
    for (; e + 3 < r1; e += 4) {
        int c0 = __builtin_amdgcn_readfirstlane(col[e]);
        int c1 = __builtin_amdgcn_readfirstlane(col[e + 1]);
        int c2 = __builtin_amdgcn_readfirstlane(col[e + 2]);
        int c3 = __builtin_amdgcn_readfirstlane(col[e + 3]);
        int s0, s1, s2, s3; float w0, w1, w2, w3;
        agg_edge_decode(c0, s0, w0); agg_edge_decode(c1, s1, w1);
        agg_edge_decode(c2, s2, w2); agg_edge_decode(c3, s3, w3);
        float2 v0 = __half22float2(g2[(size_t)s0 * 64 + lane]);
        float2 v1 = __half22float2(g2[(size_t)s1 * 64 + lane]);
        float2 v2 = __half22float2(g2[(size_t)s2 * 64 + lane]);
        float2 v3 = __half22float2(g2[(size_t)s3 * 64 + lane]);
        ax = fmaf(w0, v0.x, ax); ay = fmaf(w0, v0.y, ay);
        ax = fmaf(w1, v1.x, ax); ay = fmaf(w1, v1.y, ay);
        ax = fmaf(w2, v2.x, ax); ay = fmaf(w2, v2.y, ay);
        ax = fmaf(w3, v3.x, ax); ay = fmaf(w3, v3.y, ay);
    }
    for (; e < r1; ++e) {
        int c0 = __builtin_amdgcn_readfirstlane(col[e]);
        int s0; float w0;
        agg_edge_decode(c0, s0, w0);
        float2 v0 = __half22float2(g2[(size_t)s0 * 64 + lane]);
        ax = fmaf(w0, v0.x, ax); ay = fmaf(w0, v0.y, ay);
    }
    float2 b = ((const float2*)bias)[lane];
    float ox = fmaxf(fmaf(di, ax, b.x), 0.f);
    float oy = fmaxf(fmaf(di, ay, b.y), 0.f);
    ((__half2*)h)[(size_t)node * 64 + lane] = __floats2half2_rn(ox, oy);
}

// G[N,128] = H[N,128] @ W[128,128]; H fp16 in, G fp16 out, fp32 math.
// 32-row tile in LDS (fp32), 4x4 register blocking.
__global__ __launch_bounds__(256) void k_mm128(
        const __half* __restrict__ Hin, const float* __restrict__ W,
        __half* __restrict__ Gout, int n) {
    __shared__ float sH[32 * 128];      // 16 KB
    int row0 = blockIdx.x * 32;
    int validRows = min(32, n - row0);
    const __half2* H2 = (const __half2*)(Hin + (size_t)row0 * 128);
    float2* sH2 = (float2*)sH;
    int lim = validRows * 64;           // half2 count
    for (int t = threadIdx.x; t < 2048; t += 256)
        if (t < lim) sH2[t] = __half22float2(H2[t]);
    __syncthreads();
    int cg = threadIdx.x & 31;          // cols cg*4 .. cg*4+3
    int rg = threadIdx.x >> 5;          // rows rg*4 .. rg*4+3
    const float* h0 = sH + (rg * 4 + 0) * 128;
    const float* h1 = sH + (rg * 4 + 1) * 128;
    const float* h2 = sH + (rg * 4 + 2) * 128;
    const float* h3 = sH + (rg * 4 + 3) * 128;
    const float4* W4 = (const float4*)W;
    float4 acc0 = {0, 0, 0, 0}, acc1 = acc0, acc2 = acc0, acc3 = acc0;
#pragma unroll 8
    for (int k = 0; k < 128; k++) {
        float4 w = W4[k * 32 + cg];     // coalesced, L1/L2-resident
        float a0 = h0[k], a1 = h1[k], a2 = h2[k], a3 = h3[k];  // LDS broadcast
        acc0.x = fmaf(a0, w.x, acc0.x); acc0.y = fmaf(a0, w.y, acc0.y);
        acc0.z = fmaf(a0, w.z, acc0.z); acc0.w = fmaf(a0, w.w, acc0.w);
        acc1.x = fmaf(a1, w.x, acc1.x); acc1.y = fmaf(a1, w.y, acc1.y);
        acc1.z = fmaf(a1, w.z, acc1.z); acc1.w = fmaf(a1, w.w, acc1.w);
        acc2.x = fmaf(a2, w.x, acc2.x); acc2.y = fmaf(a2, w.y, acc2.y);
        acc2.z = fmaf(a2, w.z, acc2.z); acc2.w = fmaf(a2, w.w, acc2.w);
        acc3.x = fmaf(a3, w.x, acc3.x); acc3.y = fmaf(a3, w.y, acc3.y);
        acc3.z = fmaf(a3, w.z, acc3.z); acc3.w = fmaf(a3, w.w, acc3.w);
    }
    union { __half2 h2v[2]; uint2 u; } pk;
    int r = rg * 4;
#pragma unroll
    for (int i = 0; i < 4; i++) {
        if (row0 + r + i < n) {
            float4 a = (i == 0) ? acc0 : (i == 1) ? acc1 : (i == 2) ? acc2 : acc3;
            pk.h2v[0] = __floats2half2_rn(a.x, a.y);
            pk.h2v[1] = __floats2half2_rn(a.z, a.w);
            *(uint2*)(Gout + (size_t)(row0 + r + i) * 128 + cg * 4) = pk.u;
        }
    }
}

// batch is sorted: find per-graph node ranges (handles empty graphs)
__global__ void k_bounds(const int* __restrict__ batch, int* __restrict__ gs,
                         int n, int ng) {
    int i = blockIdx.x * 256 + threadIdx.x;
    if (i >= n) return;
    int b = batch[i];
    int prev = (i == 0) ? -1 : batch[i - 1];
    for (int g2 = prev + 1; g2 <= b; ++g2) gs[g2] = i;
    if (i == n - 1)
        for (int g2 = b + 1; g2 <= ng; ++g2) gs[g2] = n;
}

// fused mean-pool + final dense: one block (128 thr) per graph; out fp32
__global__ __launch_bounds__(128) void k_pool(
        const __half* __restrict__ h, const int* __restrict__ gs,
        const float* __restrict__ Wd2, const float* __restrict__ bd2,
        float* __restrict__ out, int n) {
    int gidx = blockIdx.x;
    int j = threadIdx.x;
    int s = gs[gidx], e2 = gs[gidx + 1];
    float acc = 0.f;
    for (int i = s; i < e2; ++i) acc += __half2float(h[(size_t)i * 128 + j]);
    float c = (float)((e2 - s) > 1 ? (e2 - s) : 1);
    __shared__ float sp[128];
    sp[j] = acc / c;
    __syncthreads();
    float o = bd2[j];
#pragma unroll 8
    for (int k = 0; k < 128; k++) o = fmaf(sp[k], Wd2[k * 128 + j], o);
    out[gidx * 128 + j] = o;
}

extern "C" void kernel_launch(void* const* d_in, const int* in_sizes, int n_in,
                              void* d_out, int out_size, void* d_ws, size_t ws_size,
                              hipStream_t stream) {
    const float* x   = (const float*)d_in[0];
    const int*  ei   = (const int*)d_in[1];
    const int* batch = (const int*)d_in[2];
    const float* Wd1 = (const float*)d_in[3];
    const float* bd1 = (const float*)d_in[4];
    const float* Wg1 = (const float*)d_in[5];
    const float* bg1 = (const float*)d_in[6];
    const float* Wg2 = (const float*)d_in[7];
    const float* bg2 = (const float*)d_in[8];
    const float* Wg3 = (const float*)d_in[9];
    const float* bg3 = (const float*)d_in[10];
    const float* Wd2 = (const float*)d_in[11];
    const float* bd2 = (const float*)d_in[12];
    float* out = (float*)d_out;

    int N  = in_sizes[0] / 4;       // N_FEAT = 4
    int E  = in_sizes[1] / 2;       // edge_index is [2, E]
    int NG = out_size / 128;        // 512 graphs
    const int* srcIdx = ei;
    const int* dstIdx = ei + E;

    char* p = (char*)d_ws;
    auto alloc = [&](size_t bytes) -> char* {
        char* r = p;
        p += (bytes + 255) & ~(size_t)255;
        return r;
    };
    int*    cnt  = (int*)alloc((size_t)N * CPAD * 4);   // padded: 1 ctr / 128B
    int*    fill = (int*)alloc((size_t)N * CPAD * 4);   // padded: 1 ctr / 128B
    int*    rp   = (int*)alloc(((size_t)N + 1) * 4);
    int*    bsum = (int*)alloc(512 * 4);
    int*    cntc = (int*)alloc((size_t)N * 4);          // compact deg copy
    float*  dis  = (float*)alloc((size_t)N * 4);
    int*    col  = (int*)alloc((size_t)E * 4);
    int*    gs   = (int*)alloc(((size_t)NG + 1) * 4);
    __half* g    = (__half*)alloc((size_t)N * 128 * 2);
    __half* h    = (__half*)alloc((size_t)N * 128 * 2);
    (void)ws_size; (void)n_in;

    hipMemsetAsync(cnt, 0, (size_t)N * CPAD * 4, stream);

    int eb  = (E + 255) / 256;
    int nb1 = (N + 255) / 256;
    int sb3 = (N + 1 + 255) / 256;
    int ab  = (N + 3) / 4;
    int mb  = (N + 31) / 32;

    k_count<<<eb, 256, 0, stream>>>(dstIdx, cnt, E);
    k_scan1<<<nb1, 256, 0, stream>>>(cnt, rp, bsum, N);
    k_scan2<<<1, 512, 0, stream>>>(bsum, nb1);
    k_scan3<<<sb3, 256, 0, stream>>>(cnt, bsum, rp, fill, cntc, dis, N, E);
    k_fill<<<eb, 256, 0, stream>>>(srcIdx, dstIdx, cntc, fill, col, E);

    k_layer1<<<(N + 1) / 2, 256, 0, stream>>>(x, Wd1, bd1, Wg1, g, N);
    k_agg<<<ab, 256, 0, stream>>>(g, rp, col, dis, bg1, h, N);
    k_mm128<<<mb, 256, 0, stream>>>(h, Wg2, g, N);
    k_agg<<<ab, 256, 0, stream>>>(g, rp, col, dis, bg2, h, N);
    k_mm128<<<mb, 256, 0, stream>>>(h, Wg3, g, N);
    k_agg<<<ab, 256, 0, stream>>>(g, rp, col, dis, bg3, h, N);

    k_bounds<<<nb1, 256, 0, stream>>>(batch, gs, N, NG);
    k_pool<<<NG, 128, 0, stream>>>(h, gs, Wd2, bd2, out, N);
}

// Round 5
// 539.415 us; speedup vs baseline: 1.5318x; 1.2061x over previous
//
#include <hip/hip_runtime.h>
#include <hip/hip_fp16.h>

// ---------------------------------------------------------------------------
// FormulaNet GCN forward: 3x GCNConv(128) + mean-pool(512 graphs) + dense.
// R2: node tensors fp16 (fp32 math) — halved the agg gather traffic. [WIN]
// R3: padded atomics [NEUTRAL: fill 128->107; limiter is scatter-write
//     sector amplification (107 MB wb for 6.4 MB payload), not atomic serialization]
// R4: CSR build rewritten as 2-level bucket sort:
//       k_cntBkt/k_scanBkt/k_binA2: bin edges into 196 buckets (512 nodes),
//         LDS-aggregated histograms, staged writes in contiguous runs;
//       k_fineB: one block per bucket: LDS hist (-> deg/rp/dis, replacing
//         k_count + 3 scan kernels), LDS scan, scatter into a 32 KB col
//         window (single-XCD L2 assembles full lines -> coalesced writeback).
//     col holds plain src; k_agg reads dis[s] via scalar load (R0 proved free).
// ---------------------------------------------------------------------------

#define BSHIFT 9
#define BSZ    512          // nodes per bucket
#define MAXBKT 256          // LDS sizing bound (N <= 131072)
#define CPAD   32           // 1 counter / 128 B line for global cursors

// ---- bucket count: LDS histogram, one global atomic per bucket per block ----
__global__ __launch_bounds__(512) void k_cntBkt(
        const int* __restrict__ dst, int* __restrict__ bktCnt, int E, int nbkt) {
    __shared__ int h[MAXBKT];
    for (int i = threadIdx.x; i < nbkt; i += 512) h[i] = 0;
    __syncthreads();
    int e0 = blockIdx.x * 4096 + threadIdx.x;
#pragma unroll
    for (int k = 0; k < 8; k++) {
        int e = e0 + k * 512;
        if (e < E) atomicAdd(&h[dst[e] >> BSHIFT], 1);
    }
    __syncthreads();
    for (int i = threadIdx.x; i < nbkt; i += 512)
        if (h[i]) atomicAdd(&bktCnt[(size_t)i * CPAD], h[i]);
}

// ---- scan bucket totals -> bktBase; seed global cursors fillB ----
__global__ __launch_bounds__(256) void k_scanBkt(
        const int* __restrict__ bktCnt, int* __restrict__ bktBase,
        int* __restrict__ fillB, int E, int nbkt) {
    __shared__ int s[256];
    int v = (threadIdx.x < nbkt) ? bktCnt[(size_t)threadIdx.x * CPAD] : 0;
    s[threadIdx.x] = v;
    for (int off = 1; off < 256; off <<= 1) {
        __syncthreads();
        int t = (threadIdx.x >= off) ? s[threadIdx.x - off] : 0;
        __syncthreads();
        s[threadIdx.x] += t;
    }
    int excl = s[threadIdx.x] - v;
    if (threadIdx.x < nbkt) {
        bktBase[threadIdx.x] = excl;
        fillB[(size_t)threadIdx.x * CPAD] = excl;
    }
    if (threadIdx.x == 0) bktBase[nbkt] = E;
}

// ---- bin edges into bucket regions; staged = (dstLocal<<17) | src ----
__global__ __launch_bounds__(512) void k_binA2(
        const int* __restrict__ src, const int* __restrict__ dst,
        int* __restrict__ fillB, int* __restrict__ staged, int E, int nbkt) {
    __shared__ int h[MAXBKT], base[MAXBKT], cur[MAXBKT];
    for (int i = threadIdx.x; i < nbkt; i += 512) { h[i] = 0; cur[i] = 0; }
    __syncthreads();
    int e0 = blockIdx.x * 4096 + threadIdx.x;
#pragma unroll
    for (int k = 0; k < 8; k++) {
        int e = e0 + k * 512;
        if (e < E) atomicAdd(&h[dst[e] >> BSHIFT], 1);
    }
    __syncthreads();
    for (int i = threadIdx.x; i < nbkt; i += 512)
        base[i] = h[i] ? atomicAdd(&fillB[(size_t)i * CPAD], h[i]) : 0;
    __syncthreads();
#pragma unroll
    for (int k = 0; k < 8; k++) {
        int e = e0 + k * 512;
        if (e < E) {
            int d = dst[e], s = src[e];
            int b = d >> BSHIFT;
            int off = atomicAdd(&cur[b], 1);
            staged[base[b] + off] = ((d & (BSZ - 1)) << 17) | s;
        }
    }
}

// ---- per-bucket: hist -> deg/rp/dis, LDS scan, window-local scatter ----
__global__ __launch_bounds__(512) void k_fineB(
        const int* __restrict__ staged, const int* __restrict__ bktBase,
        int* __restrict__ rp, float* __restrict__ dis, int* __restrict__ col,
        int N, int E, int nbkt) {
    __shared__ int cnt[BSZ];
    __shared__ int incl[BSZ];
    int b = blockIdx.x;
    int lo = bktBase[b], hi = bktBase[b + 1];
    int n0 = b << BSHIFT;
    int tid = threadIdx.x;
    cnt[tid] = 0;
    __syncthreads();
    for (int e = lo + tid; e < hi; e += 512)
        atomicAdd(&cnt[staged[e] >> 17], 1);
    __syncthreads();
    int v = cnt[tid];
    incl[tid] = v;
    for (int off = 1; off < BSZ; off <<= 1) {
        __syncthreads();
        int t = (tid >= off) ? incl[tid - off] : 0;
        __syncthreads();
        incl[tid] += t;
    }
    __syncthreads();
    int myofs = incl[tid] - v;                 // exclusive
    int node = n0 + tid;
    if (node < N) {
        rp[node]  = lo + myofs;
        dis[node] = rsqrtf((float)(v + 1));    // +1: self-loop
    }
    if (b == nbkt - 1 && tid == 0) rp[N] = E;
    // reuse incl[] as base table, cnt[] as cursors
    incl[tid] = myofs;
    cnt[tid] = 0;
    __syncthreads();
    for (int e = lo + tid; e < hi; e += 512) {
        int ent = staged[e];
        int dl = ent >> 17;
        int pos = lo + incl[dl] + atomicAdd(&cnt[dl], 1);
        col[pos] = ent & 0x1FFFF;
    }
}

// h0 = relu(x @ W_d1 + b_d1) [N,4]; g = h0 @ W_g1 [N,128] fp16 (bias deferred)
__global__ __launch_bounds__(256) void k_layer1(
        const float* __restrict__ x, const float* __restrict__ Wd1,
        const float* __restrict__ bd1, const float* __restrict__ Wg1,
        __half* __restrict__ g, int n) {
    __shared__ float sW[4 * 128];
    for (int t = threadIdx.x; t < 512; t += 256) sW[t] = Wg1[t];
    __syncthreads();
    int j = threadIdx.x & 127;
    int node = blockIdx.x * 2 + (threadIdx.x >> 7);
    if (node >= n) return;
    float4 xv = ((const float4*)x)[node];
    float acc = 0.f;
#pragma unroll
    for (int k = 0; k < 4; k++) {
        float h0 = xv.x * Wd1[k] + xv.y * Wd1[4 + k] + xv.z * Wd1[8 + k]
                 + xv.w * Wd1[12 + k] + bd1[k];
        h0 = fmaxf(h0, 0.f);
        acc = fmaf(h0, sW[k * 128 + j], acc);
    }
    g[(size_t)node * 128 + j] = __float2half_rn(acc);
}

// one wave per node; lane holds feats {2*lane, 2*lane+1} as __half2 (4 B/lane)
// col holds plain src; dis[s] is a wave-uniform scalar load (R0: perf-free)
__global__ __launch_bounds__(256) void k_agg(
        const __half* __restrict__ g, const int* __restrict__ rp,
        const int* __restrict__ col, const float* __restrict__ dis,
        const float* __restrict__ bias, __half* __restrict__ h, int n) {
    int lane = threadIdx.x & 63;
    int node = __builtin_amdgcn_readfirstlane(blockIdx.x * 4 + (threadIdx.x >> 6));
    if (node >= n) return;
    int r0 = __builtin_amdgcn_readfirstlane(rp[node]);
    int r1 = __builtin_amdgcn_readfirstlane(rp[node + 1]);
    float di = dis[node];
    const __half2* g2 = (const __half2*)g;
    float2 me = __half22float2(g2[(size_t)node * 64 + lane]);
    float ax = di * me.x, ay = di * me.y;   // self-loop term (dis_i factored out)
    int e = r0;
    for (; e + 3 < r1; e += 4) {
        int s0 = __builtin_amdgcn_readfirstlane(col[e]);
        int s1 = __builtin_amdgcn_readfirstlane(col[e + 1]);
        int s2 = __builtin_amdgcn_readfirstlane(col[e + 2]);
        int s3 = __builtin_amdgcn_readfirstlane(col[e + 3]);
        float w0 = dis[s0], w1 = dis[s1], w2 = dis[s2], w3 = dis[s3];
        float2 v0 = __half22float2(g2[(size_t)s0 * 64 + lane]);
        float2 v1 = __half22float2(g2[(size_t)s1 * 64 + lane]);
        float2 v2 = __half22float2(g2[(size_t)s2 * 64 + lane]);
        float2 v3 = __half22float2(g2[(size_t)s3 * 64 + lane]);
        ax = fmaf(w0, v0.x, ax); ay = fmaf(w0, v0.y, ay);
        ax = fmaf(w1, v1.x, ax); ay = fmaf(w1, v1.y, ay);
        ax = fmaf(w2, v2.x, ax); ay = fmaf(w2, v2.y, ay);
        ax = fmaf(w3, v3.x, ax); ay = fmaf(w3, v3.y, ay);
    }
    for (; e < r1; ++e) {
        int s0 = __builtin_amdgcn_readfirstlane(col[e]);
        float w0 = dis[s0];
        float2 v0 = __half22float2(g2[(size_t)s0 * 64 + lane]);
        ax = fmaf(w0, v0.x, ax); ay = fmaf(w0, v0.y, ay);
    }
    float2 b = ((const float2*)bias)[lane];
    float ox = fmaxf(fmaf(di, ax, b.x), 0.f);
    float oy = fmaxf(fmaf(di, ay, b.y), 0.f);
    ((__half2*)h)[(size_t)node * 64 + lane] = __floats2half2_rn(ox, oy);
}

// G[N,128] = H[N,128] @ W[128,128]; H fp16 in, G fp16 out, fp32 math.
__global__ __launch_bounds__(256) void k_mm128(
        const __half* __restrict__ Hin, const float* __restrict__ W,
        __half* __restrict__ Gout, int n) {
    __shared__ float sH[32 * 128];      // 16 KB
    int row0 = blockIdx.x * 32;
    int validRows = min(32, n - row0);
    const __half2* H2 = (const __half2*)(Hin + (size_t)row0 * 128);
    float2* sH2 = (float2*)sH;
    int lim = validRows * 64;           // half2 count
    for (int t = threadIdx.x; t < 2048; t += 256)
        if (t < lim) sH2[t] = __half22float2(H2[t]);
    __syncthreads();
    int cg = threadIdx.x & 31;          // cols cg*4 .. cg*4+3
    int rg = threadIdx.x >> 5;          // rows rg*4 .. rg*4+3
    const float* h0 = sH + (rg * 4 + 0) * 128;
    const float* h1 = sH + (rg * 4 + 1) * 128;
    const float* h2 = sH + (rg * 4 + 2) * 128;
    const float* h3 = sH + (rg * 4 + 3) * 128;
    const float4* W4 = (const float4*)W;
    float4 acc0 = {0, 0, 0, 0}, acc1 = acc0, acc2 = acc0, acc3 = acc0;
#pragma unroll 8
    for (int k = 0; k < 128; k++) {
        float4 w = W4[k * 32 + cg];
        float a0 = h0[k], a1 = h1[k], a2 = h2[k], a3 = h3[k];
        acc0.x = fmaf(a0, w.x, acc0.x); acc0.y = fmaf(a0, w.y, acc0.y);
        acc0.z = fmaf(a0, w.z, acc0.z); acc0.w = fmaf(a0, w.w, acc0.w);
        acc1.x = fmaf(a1, w.x, acc1.x); acc1.y = fmaf(a1, w.y, acc1.y);
        acc1.z = fmaf(a1, w.z, acc1.z); acc1.w = fmaf(a1, w.w, acc1.w);
        acc2.x = fmaf(a2, w.x, acc2.x); acc2.y = fmaf(a2, w.y, acc2.y);
        acc2.z = fmaf(a2, w.z, acc2.z); acc2.w = fmaf(a2, w.w, acc2.w);
        acc3.x = fmaf(a3, w.x, acc3.x); acc3.y = fmaf(a3, w.y, acc3.y);
        acc3.z = fmaf(a3, w.z, acc3.z); acc3.w = fmaf(a3, w.w, acc3.w);
    }
    union { __half2 h2v[2]; uint2 u; } pk;
    int r = rg * 4;
#pragma unroll
    for (int i = 0; i < 4; i++) {
        if (row0 + r + i < n) {
            float4 a = (i == 0) ? acc0 : (i == 1) ? acc1 : (i == 2) ? acc2 : acc3;
            pk.h2v[0] = __floats2half2_rn(a.x, a.y);
            pk.h2v[1] = __floats2half2_rn(a.z, a.w);
            *(uint2*)(Gout + (size_t)(row0 + r + i) * 128 + cg * 4) = pk.u;
        }
    }
}

// batch is sorted: find per-graph node ranges (handles empty graphs)
__global__ void k_bounds(const int* __restrict__ batch, int* __restrict__ gs,
                         int n, int ng) {
    int i = blockIdx.x * 256 + threadIdx.x;
    if (i >= n) return;
    int b = batch[i];
    int prev = (i == 0) ? -1 : batch[i - 1];
    for (int g2 = prev + 1; g2 <= b; ++g2) gs[g2] = i;
    if (i == n - 1)
        for (int g2 = b + 1; g2 <= ng; ++g2) gs[g2] = n;
}

// fused mean-pool + final dense: one block (128 thr) per graph; out fp32
__global__ __launch_bounds__(128) void k_pool(
        const __half* __restrict__ h, const int* __restrict__ gs,
        const float* __restrict__ Wd2, const float* __restrict__ bd2,
        float* __restrict__ out, int n) {
    int gidx = blockIdx.x;
    int j = threadIdx.x;
    int s = gs[gidx], e2 = gs[gidx + 1];
    float acc = 0.f;
    for (int i = s; i < e2; ++i) acc += __half2float(h[(size_t)i * 128 + j]);
    float c = (float)((e2 - s) > 1 ? (e2 - s) : 1);
    __shared__ float sp[128];
    sp[j] = acc / c;
    __syncthreads();
    float o = bd2[j];
#pragma unroll 8
    for (int k = 0; k < 128; k++) o = fmaf(sp[k], Wd2[k * 128 + j], o);
    out[gidx * 128 + j] = o;
}

extern "C" void kernel_launch(void* const* d_in, const int* in_sizes, int n_in,
                              void* d_out, int out_size, void* d_ws, size_t ws_size,
                              hipStream_t stream) {
    const float* x   = (const float*)d_in[0];
    const int*  ei   = (const int*)d_in[1];
    const int* batch = (const int*)d_in[2];
    const float* Wd1 = (const float*)d_in[3];
    const float* bd1 = (const float*)d_in[4];
    const float* Wg1 = (const float*)d_in[5];
    const float* bg1 = (const float*)d_in[6];
    const float* Wg2 = (const float*)d_in[7];
    const float* bg2 = (const float*)d_in[8];
    const float* Wg3 = (const float*)d_in[9];
    const float* bg3 = (const float*)d_in[10];
    const float* Wd2 = (const float*)d_in[11];
    const float* bd2 = (const float*)d_in[12];
    float* out = (float*)d_out;

    int N  = in_sizes[0] / 4;       // N_FEAT = 4
    int E  = in_sizes[1] / 2;       // edge_index is [2, E]
    int NG = out_size / 128;        // 512 graphs
    const int* srcIdx = ei;
    const int* dstIdx = ei + E;
    int nbkt = (N + BSZ - 1) >> BSHIFT;     // 196 for N=100000

    char* p = (char*)d_ws;
    auto alloc = [&](size_t bytes) -> char* {
        char* r = p;
        p += (bytes + 255) & ~(size_t)255;
        return r;
    };
    int*    bktCnt  = (int*)alloc((size_t)nbkt * CPAD * 4);
    int*    fillB   = (int*)alloc((size_t)nbkt * CPAD * 4);
    int*    bktBase = (int*)alloc(((size_t)nbkt + 1) * 4);
    int*    staged  = (int*)alloc((size_t)E * 4);
    int*    rp      = (int*)alloc(((size_t)N + 1) * 4);
    float*  dis     = (float*)alloc((size_t)N * 4);
    int*    col     = (int*)alloc((size_t)E * 4);
    int*    gs      = (int*)alloc(((size_t)NG + 1) * 4);
    __half* g       = (__half*)alloc((size_t)N * 128 * 2);
    __half* h       = (__half*)alloc((size_t)N * 128 * 2);
    (void)ws_size; (void)n_in;

    hipMemsetAsync(bktCnt, 0, (size_t)nbkt * CPAD * 4, stream);   // 25 KB

    int eb4 = (E + 4095) / 4096;
    int nb1 = (N + 255) / 256;
    int ab  = (N + 3) / 4;
    int mb  = (N + 31) / 32;

    k_cntBkt<<<eb4, 512, 0, stream>>>(dstIdx, bktCnt, E, nbkt);
    k_scanBkt<<<1, 256, 0, stream>>>(bktCnt, bktBase, fillB, E, nbkt);
    k_binA2<<<eb4, 512, 0, stream>>>(srcIdx, dstIdx, fillB, staged, E, nbkt);
    k_fineB<<<nbkt, 512, 0, stream>>>(staged, bktBase, rp, dis, col, N, E, nbkt);

    k_layer1<<<(N + 1) / 2, 256, 0, stream>>>(x, Wd1, bd1, Wg1, g, N);
    k_agg<<<ab, 256, 0, stream>>>(g, rp, col, dis, bg1, h, N);
    k_mm128<<<mb, 256, 0, stream>>>(h, Wg2, g, N);
    k_agg<<<ab, 256, 0, stream>>>(g, rp, col, dis, bg2, h, N);
    k_mm128<<<mb, 256, 0, stream>>>(h, Wg3, g, N);
    k_agg<<<ab, 256, 0, stream>>>(g, rp, col, dis, bg3, h, N);

    k_bounds<<<nb1, 256, 0, stream>>>(batch, gs, N, NG);
    k_pool<<<NG, 128, 0, stream>>>(h, gs, Wd2, bd2, out, N);
}

// Round 6
// 495.159 us; speedup vs baseline: 1.6687x; 1.0894x over previous
//
#include <hip/hip_runtime.h>
#include <hip/hip_fp16.h>

// ---------------------------------------------------------------------------
// FormulaNet GCN forward: 3x GCNConv(128) + mean-pool(512 graphs) + dense.
// R2: node tensors fp16 (fp32 math) — halved the agg gather traffic. [WIN]
// R3: padded atomics [NEUTRAL: limiter was scatter-write amplification]
// R4: 2-level bucket-sort CSR build (LDS hists, window-local scatter). [WIN]
// R5: pool split: k_psum (1 wave / 32-node chunk, segmented reg-accum +
//     atomic flush to sums[512][128]) + k_head (pooled/cnt + 128x128 dense).
//     Old k_pool was 8%-occupancy latency-bound: 69 us for a 25.6 MB read.
// ---------------------------------------------------------------------------

#define BSHIFT 9
#define BSZ    512          // nodes per bucket
#define MAXBKT 256          // LDS sizing bound (N <= 131072)
#define CPAD   32           // 1 counter / 128 B line for global cursors

// ---- bucket count: LDS histogram, one global atomic per bucket per block ----
__global__ __launch_bounds__(512) void k_cntBkt(
        const int* __restrict__ dst, int* __restrict__ bktCnt, int E, int nbkt) {
    __shared__ int h[MAXBKT];
    for (int i = threadIdx.x; i < nbkt; i += 512) h[i] = 0;
    __syncthreads();
    int e0 = blockIdx.x * 4096 + threadIdx.x;
#pragma unroll
    for (int k = 0; k < 8; k++) {
        int e = e0 + k * 512;
        if (e < E) atomicAdd(&h[dst[e] >> BSHIFT], 1);
    }
    __syncthreads();
    for (int i = threadIdx.x; i < nbkt; i += 512)
        if (h[i]) atomicAdd(&bktCnt[(size_t)i * CPAD], h[i]);
}

// ---- scan bucket totals -> bktBase; seed global cursors fillB ----
__global__ __launch_bounds__(256) void k_scanBkt(
        const int* __restrict__ bktCnt, int* __restrict__ bktBase,
        int* __restrict__ fillB, int E, int nbkt) {
    __shared__ int s[256];
    int v = (threadIdx.x < nbkt) ? bktCnt[(size_t)threadIdx.x * CPAD] : 0;
    s[threadIdx.x] = v;
    for (int off = 1; off < 256; off <<= 1) {
        __syncthreads();
        int t = (threadIdx.x >= off) ? s[threadIdx.x - off] : 0;
        __syncthreads();
        s[threadIdx.x] += t;
    }
    int excl = s[threadIdx.x] - v;
    if (threadIdx.x < nbkt) {
        bktBase[threadIdx.x] = excl;
        fillB[(size_t)threadIdx.x * CPAD] = excl;
    }
    if (threadIdx.x == 0) bktBase[nbkt] = E;
}

// ---- bin edges into bucket regions; staged = (dstLocal<<17) | src ----
__global__ __launch_bounds__(512) void k_binA2(
        const int* __restrict__ src, const int* __restrict__ dst,
        int* __restrict__ fillB, int* __restrict__ staged, int E, int nbkt) {
    __shared__ int h[MAXBKT], base[MAXBKT], cur[MAXBKT];
    for (int i = threadIdx.x; i < nbkt; i += 512) { h[i] = 0; cur[i] = 0; }
    __syncthreads();
    int e0 = blockIdx.x * 4096 + threadIdx.x;
#pragma unroll
    for (int k = 0; k < 8; k++) {
        int e = e0 + k * 512;
        if (e < E) atomicAdd(&h[dst[e] >> BSHIFT], 1);
    }
    __syncthreads();
    for (int i = threadIdx.x; i < nbkt; i += 512)
        base[i] = h[i] ? atomicAdd(&fillB[(size_t)i * CPAD], h[i]) : 0;
    __syncthreads();
#pragma unroll
    for (int k = 0; k < 8; k++) {
        int e = e0 + k * 512;
        if (e < E) {
            int d = dst[e], s = src[e];
            int b = d >> BSHIFT;
            int off = atomicAdd(&cur[b], 1);
            staged[base[b] + off] = ((d & (BSZ - 1)) << 17) | s;
        }
    }
}

// ---- per-bucket: hist -> deg/rp/dis, LDS scan, window-local scatter ----
__global__ __launch_bounds__(512) void k_fineB(
        const int* __restrict__ staged, const int* __restrict__ bktBase,
        int* __restrict__ rp, float* __restrict__ dis, int* __restrict__ col,
        int N, int E, int nbkt) {
    __shared__ int cnt[BSZ];
    __shared__ int incl[BSZ];
    int b = blockIdx.x;
    int lo = bktBase[b], hi = bktBase[b + 1];
    int n0 = b << BSHIFT;
    int tid = threadIdx.x;
    cnt[tid] = 0;
    __syncthreads();
    for (int e = lo + tid; e < hi; e += 512)
        atomicAdd(&cnt[staged[e] >> 17], 1);
    __syncthreads();
    int v = cnt[tid];
    incl[tid] = v;
    for (int off = 1; off < BSZ; off <<= 1) {
        __syncthreads();
        int t = (tid >= off) ? incl[tid - off] : 0;
        __syncthreads();
        incl[tid] += t;
    }
    __syncthreads();
    int myofs = incl[tid] - v;                 // exclusive
    int node = n0 + tid;
    if (node < N) {
        rp[node]  = lo + myofs;
        dis[node] = rsqrtf((float)(v + 1));    // +1: self-loop
    }
    if (b == nbkt - 1 && tid == 0) rp[N] = E;
    // reuse incl[] as base table, cnt[] as cursors
    incl[tid] = myofs;
    cnt[tid] = 0;
    __syncthreads();
    for (int e = lo + tid; e < hi; e += 512) {
        int ent = staged[e];
        int dl = ent >> 17;
        int pos = lo + incl[dl] + atomicAdd(&cnt[dl], 1);
        col[pos] = ent & 0x1FFFF;
    }
}

// h0 = relu(x @ W_d1 + b_d1) [N,4]; g = h0 @ W_g1 [N,128] fp16 (bias deferred)
__global__ __launch_bounds__(256) void k_layer1(
        const float* __restrict__ x, const float* __restrict__ Wd1,
        const float* __restrict__ bd1, const float* __restrict__ Wg1,
        __half* __restrict__ g, int n) {
    __shared__ float sW[4 * 128];
    for (int t = threadIdx.x; t < 512; t += 256) sW[t] = Wg1[t];
    __syncthreads();
    int j = threadIdx.x & 127;
    int node = blockIdx.x * 2 + (threadIdx.x >> 7);
    if (node >= n) return;
    float4 xv = ((const float4*)x)[node];
    float acc = 0.f;
#pragma unroll
    for (int k = 0; k < 4; k++) {
        float h0 = xv.x * Wd1[k] + xv.y * Wd1[4 + k] + xv.z * Wd1[8 + k]
                 + xv.w * Wd1[12 + k] + bd1[k];
        h0 = fmaxf(h0, 0.f);
        acc = fmaf(h0, sW[k * 128 + j], acc);
    }
    g[(size_t)node * 128 + j] = __float2half_rn(acc);
}

// one wave per node; lane holds feats {2*lane, 2*lane+1} as __half2 (4 B/lane)
__global__ __launch_bounds__(256) void k_agg(
        const __half* __restrict__ g, const int* __restrict__ rp,
        const int* __restrict__ col, const float* __restrict__ dis,
        const float* __restrict__ bias, __half* __restrict__ h, int n) {
    int lane = threadIdx.x & 63;
    int node = __builtin_amdgcn_readfirstlane(blockIdx.x * 4 + (threadIdx.x >> 6));
    if (node >= n) return;
    int r0 = __builtin_amdgcn_readfirstlane(rp[node]);
    int r1 = __builtin_amdgcn_readfirstlane(rp[node + 1]);
    float di = dis[node];
    const __half2* g2 = (const __half2*)g;
    float2 me = __half22float2(g2[(size_t)node * 64 + lane]);
    float ax = di * me.x, ay = di * me.y;   // self-loop term (dis_i factored out)
    int e = r0;
    for (; e + 3 < r1; e += 4) {
        int s0 = __builtin_amdgcn_readfirstlane(col[e]);
        int s1 = __builtin_amdgcn_readfirstlane(col[e + 1]);
        int s2 = __builtin_amdgcn_readfirstlane(col[e + 2]);
        int s3 = __builtin_amdgcn_readfirstlane(col[e + 3]);
        float w0 = dis[s0], w1 = dis[s1], w2 = dis[s2], w3 = dis[s3];
        float2 v0 = __half22float2(g2[(size_t)s0 * 64 + lane]);
        float2 v1 = __half22float2(g2[(size_t)s1 * 64 + lane]);
        float2 v2 = __half22float2(g2[(size_t)s2 * 64 + lane]);
        float2 v3 = __half22float2(g2[(size_t)s3 * 64 + lane]);
        ax = fmaf(w0, v0.x, ax); ay = fmaf(w0, v0.y, ay);
        ax = fmaf(w1, v1.x, ax); ay = fmaf(w1, v1.y, ay);
        ax = fmaf(w2, v2.x, ax); ay = fmaf(w2, v2.y, ay);
        ax = fmaf(w3, v3.x, ax); ay = fmaf(w3, v3.y, ay);
    }
    for (; e < r1; ++e) {
        int s0 = __builtin_amdgcn_readfirstlane(col[e]);
        float w0 = dis[s0];
        float2 v0 = __half22float2(g2[(size_t)s0 * 64 + lane]);
        ax = fmaf(w0, v0.x, ax); ay = fmaf(w0, v0.y, ay);
    }
    float2 b = ((const float2*)bias)[lane];
    float ox = fmaxf(fmaf(di, ax, b.x), 0.f);
    float oy = fmaxf(fmaf(di, ay, b.y), 0.f);
    ((__half2*)h)[(size_t)node * 64 + lane] = __floats2half2_rn(ox, oy);
}

// G[N,128] = H[N,128] @ W[128,128]; H fp16 in, G fp16 out, fp32 math.
__global__ __launch_bounds__(256) void k_mm128(
        const __half* __restrict__ Hin, const float* __restrict__ W,
        __half* __restrict__ Gout, int n) {
    __shared__ float sH[32 * 128];      // 16 KB
    int row0 = blockIdx.x * 32;
    int validRows = min(32, n - row0);
    const __half2* H2 = (const __half2*)(Hin + (size_t)row0 * 128);
    float2* sH2 = (float2*)sH;
    int lim = validRows * 64;           // half2 count
    for (int t = threadIdx.x; t < 2048; t += 256)
        if (t < lim) sH2[t] = __half22float2(H2[t]);
    __syncthreads();
    int cg = threadIdx.x & 31;          // cols cg*4 .. cg*4+3
    int rg = threadIdx.x >> 5;          // rows rg*4 .. rg*4+3
    const float* h0 = sH + (rg * 4 + 0) * 128;
    const float* h1 = sH + (rg * 4 + 1) * 128;
    const float* h2 = sH + (rg * 4 + 2) * 128;
    const float* h3 = sH + (rg * 4 + 3) * 128;
    const float4* W4 = (const float4*)W;
    float4 acc0 = {0, 0, 0, 0}, acc1 = acc0, acc2 = acc0, acc3 = acc0;
#pragma unroll 8
    for (int k = 0; k < 128; k++) {
        float4 w = W4[k * 32 + cg];
        float a0 = h0[k], a1 = h1[k], a2 = h2[k], a3 = h3[k];
        acc0.x = fmaf(a0, w.x, acc0.x); acc0.y = fmaf(a0, w.y, acc0.y);
        acc0.z = fmaf(a0, w.z, acc0.z); acc0.w = fmaf(a0, w.w, acc0.w);
        acc1.x = fmaf(a1, w.x, acc1.x); acc1.y = fmaf(a1, w.y, acc1.y);
        acc1.z = fmaf(a1, w.z, acc1.z); acc1.w = fmaf(a1, w.w, acc1.w);
        acc2.x = fmaf(a2, w.x, acc2.x); acc2.y = fmaf(a2, w.y, acc2.y);
        acc2.z = fmaf(a2, w.z, acc2.z); acc2.w = fmaf(a2, w.w, acc2.w);
        acc3.x = fmaf(a3, w.x, acc3.x); acc3.y = fmaf(a3, w.y, acc3.y);
        acc3.z = fmaf(a3, w.z, acc3.z); acc3.w = fmaf(a3, w.w, acc3.w);
    }
    union { __half2 h2v[2]; uint2 u; } pk;
    int r = rg * 4;
#pragma unroll
    for (int i = 0; i < 4; i++) {
        if (row0 + r + i < n) {
            float4 a = (i == 0) ? acc0 : (i == 1) ? acc1 : (i == 2) ? acc2 : acc3;
            pk.h2v[0] = __floats2half2_rn(a.x, a.y);
            pk.h2v[1] = __floats2half2_rn(a.z, a.w);
            *(uint2*)(Gout + (size_t)(row0 + r + i) * 128 + cg * 4) = pk.u;
        }
    }
}

// batch is sorted: find per-graph node ranges (handles empty graphs)
__global__ void k_bounds(const int* __restrict__ batch, int* __restrict__ gs,
                         int n, int ng) {
    int i = blockIdx.x * 256 + threadIdx.x;
    if (i >= n) return;
    int b = batch[i];
    int prev = (i == 0) ? -1 : batch[i - 1];
    for (int g2 = prev + 1; g2 <= b; ++g2) gs[g2] = i;
    if (i == n - 1)
        for (int g2 = b + 1; g2 <= ng; ++g2) gs[g2] = n;
}

// segmented partial-sum: one wave per 32-node chunk; lane j = feats {2j,2j+1}
__global__ __launch_bounds__(64) void k_psum(
        const __half* __restrict__ h, const int* __restrict__ batch,
        float* __restrict__ sums, int n) {
    int lane = threadIdx.x;
    int i0 = blockIdx.x * 32;
    int iend = min(i0 + 32, n);
    const __half2* h2 = (const __half2*)h;
    float ax = 0.f, ay = 0.f;
    int curb = __builtin_amdgcn_readfirstlane(batch[i0]);
    for (int i = i0; i < iend; ++i) {
        int b = __builtin_amdgcn_readfirstlane(batch[i]);
        if (b != curb) {
            atomicAdd(&sums[(size_t)curb * 128 + 2 * lane], ax);
            atomicAdd(&sums[(size_t)curb * 128 + 2 * lane + 1], ay);
            ax = 0.f; ay = 0.f; curb = b;
        }
        float2 v = __half22float2(h2[(size_t)i * 64 + lane]);
        ax += v.x; ay += v.y;
    }
    atomicAdd(&sums[(size_t)curb * 128 + 2 * lane], ax);
    atomicAdd(&sums[(size_t)curb * 128 + 2 * lane + 1], ay);
}

// head: pooled = sums/cnt; out = pooled @ Wd2 + bd2. One block per graph.
__global__ __launch_bounds__(128) void k_head(
        const float* __restrict__ sums, const int* __restrict__ gs,
        const float* __restrict__ Wd2, const float* __restrict__ bd2,
        float* __restrict__ out) {
    int gidx = blockIdx.x;
    int j = threadIdx.x;
    int c = gs[gidx + 1] - gs[gidx];
    float inv = 1.0f / (float)(c > 1 ? c : 1);
    __shared__ float sp[128];
    sp[j] = sums[(size_t)gidx * 128 + j] * inv;
    __syncthreads();
    float o = bd2[j];
#pragma unroll 8
    for (int k = 0; k < 128; k++) o = fmaf(sp[k], Wd2[k * 128 + j], o);
    out[gidx * 128 + j] = o;
}

extern "C" void kernel_launch(void* const* d_in, const int* in_sizes, int n_in,
                              void* d_out, int out_size, void* d_ws, size_t ws_size,
                              hipStream_t stream) {
    const float* x   = (const float*)d_in[0];
    const int*  ei   = (const int*)d_in[1];
    const int* batch = (const int*)d_in[2];
    const float* Wd1 = (const float*)d_in[3];
    const float* bd1 = (const float*)d_in[4];
    const float* Wg1 = (const float*)d_in[5];
    const float* bg1 = (const float*)d_in[6];
    const float* Wg2 = (const float*)d_in[7];
    const float* bg2 = (const float*)d_in[8];
    const float* Wg3 = (const float*)d_in[9];
    const float* bg3 = (const float*)d_in[10];
    const float* Wd2 = (const float*)d_in[11];
    const float* bd2 = (const float*)d_in[12];
    float* out = (float*)d_out;

    int N  = in_sizes[0] / 4;       // N_FEAT = 4
    int E  = in_sizes[1] / 2;       // edge_index is [2, E]
    int NG = out_size / 128;        // 512 graphs
    const int* srcIdx = ei;
    const int* dstIdx = ei + E;
    int nbkt = (N + BSZ - 1) >> BSHIFT;     // 196 for N=100000

    char* p = (char*)d_ws;
    auto alloc = [&](size_t bytes) -> char* {
        char* r = p;
        p += (bytes + 255) & ~(size_t)255;
        return r;
    };
    int*    bktCnt  = (int*)alloc((size_t)nbkt * CPAD * 4);
    int*    fillB   = (int*)alloc((size_t)nbkt * CPAD * 4);
    int*    bktBase = (int*)alloc(((size_t)nbkt + 1) * 4);
    int*    staged  = (int*)alloc((size_t)E * 4);
    int*    rp      = (int*)alloc(((size_t)N + 1) * 4);
    float*  dis     = (float*)alloc((size_t)N * 4);
    int*    col     = (int*)alloc((size_t)E * 4);
    int*    gs      = (int*)alloc(((size_t)NG + 1) * 4);
    float*  sums    = (float*)alloc((size_t)NG * 128 * 4);
    __half* g       = (__half*)alloc((size_t)N * 128 * 2);
    __half* h       = (__half*)alloc((size_t)N * 128 * 2);
    (void)ws_size; (void)n_in;

    hipMemsetAsync(bktCnt, 0, (size_t)nbkt * CPAD * 4, stream);   // 25 KB
    hipMemsetAsync(sums, 0, (size_t)NG * 128 * 4, stream);        // 256 KB

    int eb4 = (E + 4095) / 4096;
    int nb1 = (N + 255) / 256;
    int ab  = (N + 3) / 4;
    int mb  = (N + 31) / 32;
    int pb  = (N + 31) / 32;

    k_cntBkt<<<eb4, 512, 0, stream>>>(dstIdx, bktCnt, E, nbkt);
    k_scanBkt<<<1, 256, 0, stream>>>(bktCnt, bktBase, fillB, E, nbkt);
    k_binA2<<<eb4, 512, 0, stream>>>(srcIdx, dstIdx, fillB, staged, E, nbkt);
    k_fineB<<<nbkt, 512, 0, stream>>>(staged, bktBase, rp, dis, col, N, E, nbkt);

    k_layer1<<<(N + 1) / 2, 256, 0, stream>>>(x, Wd1, bd1, Wg1, g, N);
    k_agg<<<ab, 256, 0, stream>>>(g, rp, col, dis, bg1, h, N);
    k_mm128<<<mb, 256, 0, stream>>>(h, Wg2, g, N);
    k_agg<<<ab, 256, 0, stream>>>(g, rp, col, dis, bg2, h, N);
    k_mm128<<<mb, 256, 0, stream>>>(h, Wg3, g, N);
    k_agg<<<ab, 256, 0, stream>>>(g, rp, col, dis, bg3, h, N);

    k_bounds<<<nb1, 256, 0, stream>>>(batch, gs, N, NG);
    k_psum<<<pb, 64, 0, stream>>>(h, batch, sums, N);
    k_head<<<NG, 128, 0, stream>>>(sums, gs, Wd2, bd2, out);
}

// Round 7
// 452.304 us; speedup vs baseline: 1.8268x; 1.0947x over previous
//
#include <hip/hip_runtime.h>
#include <hip/hip_fp16.h>

// ---------------------------------------------------------------------------
// FormulaNet GCN forward: 3x GCNConv(128) + mean-pool(512 graphs) + dense.
// R2: node tensors fp16 (fp32 math) — halved agg gather traffic. [WIN]
// R4: 2-level bucket-sort CSR build. [WIN]
// R5: pool split into k_psum + k_head. [WIN: 69 -> ~12 us]
// R6: (a) mm via mfma_f32_16x16x32_f16 (W pre-converted fp16, transposed) —
//         mm becomes memory-bound ~10us; (b) buckets 512->256 nodes (fineB
//         196->391 blocks, was <1 block/CU); (c) psum 256-thr blocks.
// k_agg is at ~6.0 TB/s effective gather (95% of streaming ceiling) — left alone.
// ---------------------------------------------------------------------------

#define BSHIFT 8
#define BSZ    256          // nodes per bucket
#define MAXBKT 512          // LDS sizing bound (N <= 131072)
#define CPAD   32           // 1 counter / 128 B line for global cursors

typedef _Float16 half8 __attribute__((ext_vector_type(8)));
typedef float f32x4 __attribute__((ext_vector_type(4)));

// ---- bucket count: LDS histogram, one global atomic per bucket per block ----
__global__ __launch_bounds__(512) void k_cntBkt(
        const int* __restrict__ dst, int* __restrict__ bktCnt, int E, int nbkt) {
    __shared__ int h[MAXBKT];
    for (int i = threadIdx.x; i < nbkt; i += 512) h[i] = 0;
    __syncthreads();
    int e0 = blockIdx.x * 4096 + threadIdx.x;
#pragma unroll
    for (int k = 0; k < 8; k++) {
        int e = e0 + k * 512;
        if (e < E) atomicAdd(&h[dst[e] >> BSHIFT], 1);
    }
    __syncthreads();
    for (int i = threadIdx.x; i < nbkt; i += 512)
        if (h[i]) atomicAdd(&bktCnt[(size_t)i * CPAD], h[i]);
}

// ---- scan bucket totals (<=512) -> bktBase; seed global cursors fillB ----
__global__ __launch_bounds__(512) void k_scanBkt(
        const int* __restrict__ bktCnt, int* __restrict__ bktBase,
        int* __restrict__ fillB, int E, int nbkt) {
    __shared__ int s[512];
    int v = (threadIdx.x < nbkt) ? bktCnt[(size_t)threadIdx.x * CPAD] : 0;
    s[threadIdx.x] = v;
    for (int off = 1; off < 512; off <<= 1) {
        __syncthreads();
        int t = (threadIdx.x >= off) ? s[threadIdx.x - off] : 0;
        __syncthreads();
        s[threadIdx.x] += t;
    }
    int excl = s[threadIdx.x] - v;
    if (threadIdx.x < nbkt) {
        bktBase[threadIdx.x] = excl;
        fillB[(size_t)threadIdx.x * CPAD] = excl;
    }
    if (threadIdx.x == 0) bktBase[nbkt] = E;
}

// ---- bin edges into bucket regions; staged = (dstLocal<<17) | src ----
__global__ __launch_bounds__(512) void k_binA2(
        const int* __restrict__ src, const int* __restrict__ dst,
        int* __restrict__ fillB, int* __restrict__ staged, int E, int nbkt) {
    __shared__ int h[MAXBKT], base[MAXBKT], cur[MAXBKT];
    for (int i = threadIdx.x; i < nbkt; i += 512) { h[i] = 0; cur[i] = 0; }
    __syncthreads();
    int e0 = blockIdx.x * 4096 + threadIdx.x;
#pragma unroll
    for (int k = 0; k < 8; k++) {
        int e = e0 + k * 512;
        if (e < E) atomicAdd(&h[dst[e] >> BSHIFT], 1);
    }
    __syncthreads();
    for (int i = threadIdx.x; i < nbkt; i += 512)
        base[i] = h[i] ? atomicAdd(&fillB[(size_t)i * CPAD], h[i]) : 0;
    __syncthreads();
#pragma unroll
    for (int k = 0; k < 8; k++) {
        int e = e0 + k * 512;
        if (e < E) {
            int d = dst[e], s = src[e];
            int b = d >> BSHIFT;
            int off = atomicAdd(&cur[b], 1);
            staged[base[b] + off] = ((d & (BSZ - 1)) << 17) | s;
        }
    }
}

// ---- per-bucket: hist -> deg/rp/dis, LDS scan, window-local scatter ----
__global__ __launch_bounds__(512) void k_fineB(
        const int* __restrict__ staged, const int* __restrict__ bktBase,
        int* __restrict__ rp, float* __restrict__ dis, int* __restrict__ col,
        int N, int E, int nbkt) {
    __shared__ int cnt[BSZ];
    __shared__ int incl[BSZ];
    int b = blockIdx.x;
    int lo = bktBase[b], hi = bktBase[b + 1];
    int n0 = b << BSHIFT;
    int tid = threadIdx.x;
    if (tid < BSZ) cnt[tid] = 0;
    __syncthreads();
    for (int e = lo + tid; e < hi; e += 512)
        atomicAdd(&cnt[staged[e] >> 17], 1);
    __syncthreads();
    int v = 0;
    if (tid < BSZ) { v = cnt[tid]; incl[tid] = v; }
    for (int off = 1; off < BSZ; off <<= 1) {
        __syncthreads();
        int t = (tid < BSZ && tid >= off) ? incl[tid - off] : 0;
        __syncthreads();
        if (tid < BSZ) incl[tid] += t;
    }
    __syncthreads();
    int myofs = 0;
    if (tid < BSZ) {
        myofs = incl[tid] - v;                 // exclusive
        int node = n0 + tid;
        if (node < N) {
            rp[node]  = lo + myofs;
            dis[node] = rsqrtf((float)(v + 1));    // +1: self-loop
        }
    }
    if (b == nbkt - 1 && tid == 0) rp[N] = E;
    __syncthreads();
    // reuse incl[] as base table, cnt[] as cursors
    if (tid < BSZ) { incl[tid] = myofs; cnt[tid] = 0; }
    __syncthreads();
    for (int e = lo + tid; e < hi; e += 512) {
        int ent = staged[e];
        int dl = ent >> 17;
        int pos = lo + incl[dl] + atomicAdd(&cnt[dl], 1);
        col[pos] = ent & 0x1FFFF;
    }
}

// W fp32 [128,128] -> WT fp16 transposed [n][k] (B-frag-friendly), both layers
__global__ __launch_bounds__(256) void k_cvtW(
        const float* __restrict__ W2, const float* __restrict__ W3,
        __half* __restrict__ WT2, __half* __restrict__ WT3) {
    int t = blockIdx.x * 256 + threadIdx.x;     // 0..16383
    int k = t >> 7, n = t & 127;
    WT2[n * 128 + k] = __float2half_rn(W2[t]);
    WT3[n * 128 + k] = __float2half_rn(W3[t]);
}

// h0 = relu(x @ W_d1 + b_d1) [N,4]; g = h0 @ W_g1 [N,128] fp16 (bias deferred)
__global__ __launch_bounds__(256) void k_layer1(
        const float* __restrict__ x, const float* __restrict__ Wd1,
        const float* __restrict__ bd1, const float* __restrict__ Wg1,
        __half* __restrict__ g, int n) {
    __shared__ float sW[4 * 128];
    for (int t = threadIdx.x; t < 512; t += 256) sW[t] = Wg1[t];
    __syncthreads();
    int j = threadIdx.x & 127;
    int node = blockIdx.x * 2 + (threadIdx.x >> 7);
    if (node >= n) return;
    float4 xv = ((const float4*)x)[node];
    float acc = 0.f;
#pragma unroll
    for (int k = 0; k < 4; k++) {
        float h0 = xv.x * Wd1[k] + xv.y * Wd1[4 + k] + xv.z * Wd1[8 + k]
                 + xv.w * Wd1[12 + k] + bd1[k];
        h0 = fmaxf(h0, 0.f);
        acc = fmaf(h0, sW[k * 128 + j], acc);
    }
    g[(size_t)node * 128 + j] = __float2half_rn(acc);
}

// one wave per node; lane holds feats {2*lane, 2*lane+1} as __half2 (4 B/lane)
__global__ __launch_bounds__(256) void k_agg(
        const __half* __restrict__ g, const int* __restrict__ rp,
        const int* __restrict__ col, const float* __restrict__ dis,
        const float* __restrict__ bias, __half* __restrict__ h, int n) {
    int lane = threadIdx.x & 63;
    int node = __builtin_amdgcn_readfirstlane(blockIdx.x * 4 + (threadIdx.x >> 6));
    if (node >= n) return;
    int r0 = __builtin_amdgcn_readfirstlane(rp[node]);
    int r1 = __builtin_amdgcn_readfirstlane(rp[node + 1]);
    float di = dis[node];
    const __half2* g2 = (const __half2*)g;
    float2 me = __half22float2(g2[(size_t)node * 64 + lane]);
    float ax = di * me.x, ay = di * me.y;   // self-loop term (dis_i factored out)
    int e = r0;
    for (; e + 3 < r1; e += 4) {
        int s0 = __builtin_amdgcn_readfirstlane(col[e]);
        int s1 = __builtin_amdgcn_readfirstlane(col[e + 1]);
        int s2 = __builtin_amdgcn_readfirstlane(col[e + 2]);
        int s3 = __builtin_amdgcn_readfirstlane(col[e + 3]);
        float w0 = dis[s0], w1 = dis[s1], w2 = dis[s2], w3 = dis[s3];
        float2 v0 = __half22float2(g2[(size_t)s0 * 64 + lane]);
        float2 v1 = __half22float2(g2[(size_t)s1 * 64 + lane]);
        float2 v2 = __half22float2(g2[(size_t)s2 * 64 + lane]);
        float2 v3 = __half22float2(g2[(size_t)s3 * 64 + lane]);
        ax = fmaf(w0, v0.x, ax); ay = fmaf(w0, v0.y, ay);
        ax = fmaf(w1, v1.x, ax); ay = fmaf(w1, v1.y, ay);
        ax = fmaf(w2, v2.x, ax); ay = fmaf(w2, v2.y, ay);
        ax = fmaf(w3, v3.x, ax); ay = fmaf(w3, v3.y, ay);
    }
    for (; e < r1; ++e) {
        int s0 = __builtin_amdgcn_readfirstlane(col[e]);
        float w0 = dis[s0];
        float2 v0 = __half22float2(g2[(size_t)s0 * 64 + lane]);
        ax = fmaf(w0, v0.x, ax); ay = fmaf(w0, v0.y, ay);
    }
    float2 b = ((const float2*)bias)[lane];
    float ox = fmaxf(fmaf(di, ax, b.x), 0.f);
    float oy = fmaxf(fmaf(di, ay, b.y), 0.f);
    ((__half2*)h)[(size_t)node * 64 + lane] = __floats2half2_rn(ox, oy);
}

// G[N,128] = H[N,128] @ W[128,128] via mfma_f32_16x16x32_f16.
// Block: 16 rows, 4 waves; wave w covers cols [w*32, w*32+32).
// A frag: m=lane&15, k=quad*8+j (from LDS, +8-half pad to spread banks).
// B frag: n=lane&15, k=quad*8+j (16B contiguous from WT[n][k], L1-resident).
// C/D: col=lane&15, row=quad*4+reg. Epilogue via LDS for coalesced stores.
__global__ __launch_bounds__(256) void k_mmMFMA(
        const __half* __restrict__ Hin, const __half* __restrict__ WT,
        __half* __restrict__ Gout, int n) {
    __shared__ _Float16 sH[16 * 136];
    __shared__ _Float16 sO[16 * 136];
    int row0 = blockIdx.x * 16;
    int t = threadIdx.x;
    int lr = t >> 4, seg = t & 15;
    if (row0 + lr < n)
        *(uint4*)&sH[lr * 136 + seg * 8] =
            *(const uint4*)(Hin + (size_t)(row0 + lr) * 128 + seg * 8);
    __syncthreads();
    int wave = t >> 6, lane = t & 63;
    int q = lane >> 4, c = lane & 15;
    int n0 = wave * 32;
    f32x4 acc0 = {0.f, 0.f, 0.f, 0.f}, acc1 = {0.f, 0.f, 0.f, 0.f};
#pragma unroll
    for (int ks = 0; ks < 4; ks++) {
        int k0 = ks * 32;
        half8 a  = *(half8*)&sH[c * 136 + k0 + q * 8];
        half8 b0 = *(const half8*)(WT + (size_t)(n0 + c) * 128 + k0 + q * 8);
        half8 b1 = *(const half8*)(WT + (size_t)(n0 + 16 + c) * 128 + k0 + q * 8);
        acc0 = __builtin_amdgcn_mfma_f32_16x16x32_f16(a, b0, acc0, 0, 0, 0);
        acc1 = __builtin_amdgcn_mfma_f32_16x16x32_f16(a, b1, acc1, 0, 0, 0);
    }
#pragma unroll
    for (int r = 0; r < 4; r++) {
        sO[(q * 4 + r) * 136 + n0 + c]      = (_Float16)acc0[r];
        sO[(q * 4 + r) * 136 + n0 + 16 + c] = (_Float16)acc1[r];
    }
    __syncthreads();
    if (row0 + lr < n)
        *(uint4*)(Gout + (size_t)(row0 + lr) * 128 + seg * 8) =
            *(uint4*)&sO[lr * 136 + seg * 8];
}

// batch is sorted: find per-graph node ranges (handles empty graphs)
__global__ void k_bounds(const int* __restrict__ batch, int* __restrict__ gs,
                         int n, int ng) {
    int i = blockIdx.x * 256 + threadIdx.x;
    if (i >= n) return;
    int b = batch[i];
    int prev = (i == 0) ? -1 : batch[i - 1];
    for (int g2 = prev + 1; g2 <= b; ++g2) gs[g2] = i;
    if (i == n - 1)
        for (int g2 = b + 1; g2 <= ng; ++g2) gs[g2] = n;
}

// segmented partial-sum: 4 waves/block, one wave per 32-node chunk
__global__ __launch_bounds__(256) void k_psum(
        const __half* __restrict__ h, const int* __restrict__ batch,
        float* __restrict__ sums, int n) {
    int lane = threadIdx.x & 63;
    int chunk = blockIdx.x * 4 + (threadIdx.x >> 6);
    int i0 = chunk * 32;
    if (i0 >= n) return;
    int iend = min(i0 + 32, n);
    const __half2* h2 = (const __half2*)h;
    float ax = 0.f, ay = 0.f;
    int curb = __builtin_amdgcn_readfirstlane(batch[i0]);
    for (int i = i0; i < iend; ++i) {
        int b = __builtin_amdgcn_readfirstlane(batch[i]);
        if (b != curb) {
            atomicAdd(&sums[(size_t)curb * 128 + 2 * lane], ax);
            atomicAdd(&sums[(size_t)curb * 128 + 2 * lane + 1], ay);
            ax = 0.f; ay = 0.f; curb = b;
        }
        float2 v = __half22float2(h2[(size_t)i * 64 + lane]);
        ax += v.x; ay += v.y;
    }
    atomicAdd(&sums[(size_t)curb * 128 + 2 * lane], ax);
    atomicAdd(&sums[(size_t)curb * 128 + 2 * lane + 1], ay);
}

// head: pooled = sums/cnt; out = pooled @ Wd2 + bd2. One block per graph.
__global__ __launch_bounds__(128) void k_head(
        const float* __restrict__ sums, const int* __restrict__ gs,
        const float* __restrict__ Wd2, const float* __restrict__ bd2,
        float* __restrict__ out) {
    int gidx = blockIdx.x;
    int j = threadIdx.x;
    int c = gs[gidx + 1] - gs[gidx];
    float inv = 1.0f / (float)(c > 1 ? c : 1);
    __shared__ float sp[128];
    sp[j] = sums[(size_t)gidx * 128 + j] * inv;
    __syncthreads();
    float o = bd2[j];
#pragma unroll 8
    for (int k = 0; k < 128; k++) o = fmaf(sp[k], Wd2[k * 128 + j], o);
    out[gidx * 128 + j] = o;
}

extern "C" void kernel_launch(void* const* d_in, const int* in_sizes, int n_in,
                              void* d_out, int out_size, void* d_ws, size_t ws_size,
                              hipStream_t stream) {
    const float* x   = (const float*)d_in[0];
    const int*  ei   = (const int*)d_in[1];
    const int* batch = (const int*)d_in[2];
    const float* Wd1 = (const float*)d_in[3];
    const float* bd1 = (const float*)d_in[4];
    const float* Wg1 = (const float*)d_in[5];
    const float* bg1 = (const float*)d_in[6];
    const float* Wg2 = (const float*)d_in[7];
    const float* bg2 = (const float*)d_in[8];
    const float* Wg3 = (const float*)d_in[9];
    const float* bg3 = (const float*)d_in[10];
    const float* Wd2 = (const float*)d_in[11];
    const float* bd2 = (const float*)d_in[12];
    float* out = (float*)d_out;

    int N  = in_sizes[0] / 4;       // N_FEAT = 4
    int E  = in_sizes[1] / 2;       // edge_index is [2, E]
    int NG = out_size / 128;        // 512 graphs
    const int* srcIdx = ei;
    const int* dstIdx = ei + E;
    int nbkt = (N + BSZ - 1) >> BSHIFT;     // 391 for N=100000

    char* p = (char*)d_ws;
    auto alloc = [&](size_t bytes) -> char* {
        char* r = p;
        p += (bytes + 255) & ~(size_t)255;
        return r;
    };
    int*    bktCnt  = (int*)alloc((size_t)nbkt * CPAD * 4);
    int*    fillB   = (int*)alloc((size_t)nbkt * CPAD * 4);
    int*    bktBase = (int*)alloc(((size_t)nbkt + 1) * 4);
    int*    staged  = (int*)alloc((size_t)E * 4);
    int*    rp      = (int*)alloc(((size_t)N + 1) * 4);
    float*  dis     = (float*)alloc((size_t)N * 4);
    int*    col     = (int*)alloc((size_t)E * 4);
    int*    gs      = (int*)alloc(((size_t)NG + 1) * 4);
    float*  sums    = (float*)alloc((size_t)NG * 128 * 4);
    __half* WT2     = (__half*)alloc(16384 * 2);
    __half* WT3     = (__half*)alloc(16384 * 2);
    __half* g       = (__half*)alloc((size_t)N * 128 * 2);
    __half* h       = (__half*)alloc((size_t)N * 128 * 2);
    (void)ws_size; (void)n_in;

    hipMemsetAsync(bktCnt, 0, (size_t)nbkt * CPAD * 4, stream);   // 50 KB
    hipMemsetAsync(sums, 0, (size_t)NG * 128 * 4, stream);        // 256 KB

    int eb4 = (E + 4095) / 4096;
    int nb1 = (N + 255) / 256;
    int ab  = (N + 3) / 4;
    int mmb = (N + 15) / 16;
    int pb  = (N + 127) / 128;

    k_cntBkt<<<eb4, 512, 0, stream>>>(dstIdx, bktCnt, E, nbkt);
    k_scanBkt<<<1, 512, 0, stream>>>(bktCnt, bktBase, fillB, E, nbkt);
    k_binA2<<<eb4, 512, 0, stream>>>(srcIdx, dstIdx, fillB, staged, E, nbkt);
    k_fineB<<<nbkt, 512, 0, stream>>>(staged, bktBase, rp, dis, col, N, E, nbkt);

    k_cvtW<<<64, 256, 0, stream>>>(Wg2, Wg3, WT2, WT3);
    k_layer1<<<(N + 1) / 2, 256, 0, stream>>>(x, Wd1, bd1, Wg1, g, N);
    k_agg<<<ab, 256, 0, stream>>>(g, rp, col, dis, bg1, h, N);
    k_mmMFMA<<<mmb, 256, 0, stream>>>(h, WT2, g, N);
    k_agg<<<ab, 256, 0, stream>>>(g, rp, col, dis, bg2, h, N);
    k_mmMFMA<<<mmb, 256, 0, stream>>>(h, WT3, g, N);
    k_agg<<<ab, 256, 0, stream>>>(g, rp, col, dis, bg3, h, N);

    k_bounds<<<nb1, 256, 0, stream>>>(batch, gs, N, NG);
    k_psum<<<pb, 256, 0, stream>>>(h, batch, sums, N);
    k_head<<<NG, 128, 0, stream>>>(sums, gs, Wd2, bd2, out);
}

// Round 8
// 439.715 us; speedup vs baseline: 1.8791x; 1.0286x over previous
//
#include <hip/hip_runtime.h>
#include <hip/hip_fp16.h>

// ---------------------------------------------------------------------------
// FormulaNet GCN forward: 3x GCNConv(128) + mean-pool(512 graphs) + dense.
// R2: node tensors fp16 (fp32 math) — halved agg gather traffic. [WIN]
// R4: bucket-sort CSR build (no global-atomic scatter). [WIN]
// R5: pool split into k_psum + k_head. [WIN]
// R6: mm via mfma_f32_16x16x32_f16; 256-node buckets. [WIN]
// R7: dispatch-graph collapse 18 -> 10:
//     (a) single-pass CSR: fixed-capacity bucket regions (CAP=8192, 64-sigma
//         margin over Poisson(4096)) -> k_bin reserves via global atomicAdd;
//         cntBkt/scanBkt/memsets eliminated; rp -> rpA/reA (start/end).
//     (b) k_prep mega-kernel: layer1 + cvtW + bounds + zero(bktFill,sums)
//         as disjoint blockIdx ranges.
// k_agg pinned at 461 MB logical / 68.3 us = 6.7 TB/s processed — left alone.
// ---------------------------------------------------------------------------

#define BSHIFT 8
#define BSZ    256          // nodes per bucket
#define MAXBKT 512          // LDS sizing bound (N <= 131072)
#define CPAD   32           // 1 counter / 128 B line for global cursors
#define CAPSH  13
#define CAP    8192         // staged/col slots per bucket

typedef _Float16 half8 __attribute__((ext_vector_type(8)));
typedef float f32x4 __attribute__((ext_vector_type(4)));

// ---- prep: layer1 | cvtW | bounds | zero(bktFill, sums), by block range ----
__global__ __launch_bounds__(256) void k_prep(
        const float* __restrict__ x, const float* __restrict__ Wd1,
        const float* __restrict__ bd1, const float* __restrict__ Wg1,
        __half* __restrict__ g,
        const float* __restrict__ W2, const float* __restrict__ W3,
        __half* __restrict__ WT2, __half* __restrict__ WT3,
        const int* __restrict__ batch, int* __restrict__ gs,
        int* __restrict__ bktFill, float* __restrict__ sums,
        int N, int NG, int nbkt, int L1B, int NB1) {
    __shared__ float sW[4 * 128];
    int bid = blockIdx.x;
    if (bid < L1B) {
        // ---- layer1: h0 = relu(x@Wd1+bd1); g = h0@Wg1 (fp16, bias deferred)
        for (int t = threadIdx.x; t < 512; t += 256) sW[t] = Wg1[t];
        __syncthreads();
        int j = threadIdx.x & 127;
        int node = bid * 2 + (threadIdx.x >> 7);
        if (node >= N) return;
        float4 xv = ((const float4*)x)[node];
        float acc = 0.f;
#pragma unroll
        for (int k = 0; k < 4; k++) {
            float h0 = xv.x * Wd1[k] + xv.y * Wd1[4 + k] + xv.z * Wd1[8 + k]
                     + xv.w * Wd1[12 + k] + bd1[k];
            h0 = fmaxf(h0, 0.f);
            acc = fmaf(h0, sW[k * 128 + j], acc);
        }
        g[(size_t)node * 128 + j] = __float2half_rn(acc);
    } else if (bid < L1B + 64) {
        // ---- cvtW: W fp32 [k][n] -> WT fp16 [n][k], both layers
        int t = (bid - L1B) * 256 + threadIdx.x;    // 0..16383
        int k = t >> 7, nn = t & 127;
        WT2[nn * 128 + k] = __float2half_rn(W2[t]);
        WT3[nn * 128 + k] = __float2half_rn(W3[t]);
    } else if (bid < L1B + 64 + NB1) {
        // ---- bounds: batch sorted -> per-graph node ranges
        int i = (bid - L1B - 64) * 256 + threadIdx.x;
        if (i >= N) return;
        int b = batch[i];
        int prev = (i == 0) ? -1 : batch[i - 1];
        for (int g2 = prev + 1; g2 <= b; ++g2) gs[g2] = i;
        if (i == N - 1)
            for (int g2 = b + 1; g2 <= NG; ++g2) gs[g2] = N;
    } else {
        // ---- zero bktFill (nbkt*CPAD ints) then sums (NG*128 floats)
        int nz = nbkt * CPAD;
        int idx = (bid - L1B - 64 - NB1) * 256 + threadIdx.x;
        if (idx < nz) bktFill[idx] = 0;
        else if (idx - nz < NG * 128) sums[idx - nz] = 0.f;
    }
}

// ---- single-pass binning: LDS hist -> one reservation/bucket/block ->
//      staged[(b<<CAPSH) + off] = (dstLocal<<17) | src ----
__global__ __launch_bounds__(512) void k_bin(
        const int* __restrict__ src, const int* __restrict__ dst,
        int* __restrict__ bktFill, int* __restrict__ staged, int E, int nbkt) {
    __shared__ int h[MAXBKT], base[MAXBKT], cur[MAXBKT];
    for (int i = threadIdx.x; i < nbkt; i += 512) { h[i] = 0; cur[i] = 0; }
    __syncthreads();
    int e0 = blockIdx.x * 4096 + threadIdx.x;
#pragma unroll
    for (int k = 0; k < 8; k++) {
        int e = e0 + k * 512;
        if (e < E) atomicAdd(&h[dst[e] >> BSHIFT], 1);
    }
    __syncthreads();
    for (int i = threadIdx.x; i < nbkt; i += 512)
        base[i] = h[i] ? atomicAdd(&bktFill[(size_t)i * CPAD], h[i]) : 0;
    __syncthreads();
#pragma unroll
    for (int k = 0; k < 8; k++) {
        int e = e0 + k * 512;
        if (e < E) {
            int d = dst[e], s = src[e];
            int b = d >> BSHIFT;
            int off = atomicAdd(&cur[b], 1);
            staged[((size_t)b << CAPSH) + base[b] + off] = ((d & (BSZ - 1)) << 17) | s;
        }
    }
}

// ---- per-bucket: hist -> deg/rpA/reA/dis, LDS scan, window-local scatter ----
__global__ __launch_bounds__(512) void k_fineB(
        const int* __restrict__ staged, const int* __restrict__ bktFill,
        int* __restrict__ rpA, int* __restrict__ reA, float* __restrict__ dis,
        int* __restrict__ col, int N) {
    __shared__ int cnt[BSZ];
    __shared__ int incl[BSZ];
    int b = blockIdx.x;
    int lo = b << CAPSH;
    int cntE = bktFill[(size_t)b * CPAD];
    int n0 = b << BSHIFT;
    int tid = threadIdx.x;
    if (tid < BSZ) cnt[tid] = 0;
    __syncthreads();
    for (int e = tid; e < cntE; e += 512)
        atomicAdd(&cnt[staged[lo + e] >> 17], 1);
    __syncthreads();
    int v = 0;
    if (tid < BSZ) { v = cnt[tid]; incl[tid] = v; }
    for (int off = 1; off < BSZ; off <<= 1) {
        __syncthreads();
        int t = (tid < BSZ && tid >= off) ? incl[tid - off] : 0;
        __syncthreads();
        if (tid < BSZ) incl[tid] += t;
    }
    __syncthreads();
    int myofs = 0;
    if (tid < BSZ) {
        myofs = incl[tid] - v;                 // exclusive
        int node = n0 + tid;
        if (node < N) {
            rpA[node] = lo + myofs;
            reA[node] = lo + myofs + v;
            dis[node] = rsqrtf((float)(v + 1));    // +1: self-loop
        }
    }
    __syncthreads();
    // reuse incl[] as base table, cnt[] as cursors
    if (tid < BSZ) { incl[tid] = myofs; cnt[tid] = 0; }
    __syncthreads();
    for (int e = tid; e < cntE; e += 512) {
        int ent = staged[lo + e];
        int dl = ent >> 17;
        int pos = lo + incl[dl] + atomicAdd(&cnt[dl], 1);
        col[pos] = ent & 0x1FFFF;
    }
}

// one wave per node; lane holds feats {2*lane, 2*lane+1} as __half2 (4 B/lane)
__global__ __launch_bounds__(256) void k_agg(
        const __half* __restrict__ g, const int* __restrict__ rpA,
        const int* __restrict__ reA, const int* __restrict__ col,
        const float* __restrict__ dis, const float* __restrict__ bias,
        __half* __restrict__ h, int n) {
    int lane = threadIdx.x & 63;
    int node = __builtin_amdgcn_readfirstlane(blockIdx.x * 4 + (threadIdx.x >> 6));
    if (node >= n) return;
    int r0 = __builtin_amdgcn_readfirstlane(rpA[node]);
    int r1 = __builtin_amdgcn_readfirstlane(reA[node]);
    float di = dis[node];
    const __half2* g2 = (const __half2*)g;
    float2 me = __half22float2(g2[(size_t)node * 64 + lane]);
    float ax = di * me.x, ay = di * me.y;   // self-loop term (dis_i factored out)
    int e = r0;
    for (; e + 3 < r1; e += 4) {
        int s0 = __builtin_amdgcn_readfirstlane(col[e]);
        int s1 = __builtin_amdgcn_readfirstlane(col[e + 1]);
        int s2 = __builtin_amdgcn_readfirstlane(col[e + 2]);
        int s3 = __builtin_amdgcn_readfirstlane(col[e + 3]);
        float w0 = dis[s0], w1 = dis[s1], w2 = dis[s2], w3 = dis[s3];
        float2 v0 = __half22float2(g2[(size_t)s0 * 64 + lane]);
        float2 v1 = __half22float2(g2[(size_t)s1 * 64 + lane]);
        float2 v2 = __half22float2(g2[(size_t)s2 * 64 + lane]);
        float2 v3 = __half22float2(g2[(size_t)s3 * 64 + lane]);
        ax = fmaf(w0, v0.x, ax); ay = fmaf(w0, v0.y, ay);
        ax = fmaf(w1, v1.x, ax); ay = fmaf(w1, v1.y, ay);
        ax = fmaf(w2, v2.x, ax); ay = fmaf(w2, v2.y, ay);
        ax = fmaf(w3, v3.x, ax); ay = fmaf(w3, v3.y, ay);
    }
    for (; e < r1; ++e) {
        int s0 = __builtin_amdgcn_readfirstlane(col[e]);
        float w0 = dis[s0];
        float2 v0 = __half22float2(g2[(size_t)s0 * 64 + lane]);
        ax = fmaf(w0, v0.x, ax); ay = fmaf(w0, v0.y, ay);
    }
    float2 b = ((const float2*)bias)[lane];
    float ox = fmaxf(fmaf(di, ax, b.x), 0.f);
    float oy = fmaxf(fmaf(di, ay, b.y), 0.f);
    ((__half2*)h)[(size_t)node * 64 + lane] = __floats2half2_rn(ox, oy);
}

// G[N,128] = H[N,128] @ W[128,128] via mfma_f32_16x16x32_f16.
__global__ __launch_bounds__(256) void k_mmMFMA(
        const __half* __restrict__ Hin, const __half* __restrict__ WT,
        __half* __restrict__ Gout, int n) {
    __shared__ _Float16 sH[16 * 136];
    __shared__ _Float16 sO[16 * 136];
    int row0 = blockIdx.x * 16;
    int t = threadIdx.x;
    int lr = t >> 4, seg = t & 15;
    if (row0 + lr < n)
        *(uint4*)&sH[lr * 136 + seg * 8] =
            *(const uint4*)(Hin + (size_t)(row0 + lr) * 128 + seg * 8);
    __syncthreads();
    int wave = t >> 6, lane = t & 63;
    int q = lane >> 4, c = lane & 15;
    int n0 = wave * 32;
    f32x4 acc0 = {0.f, 0.f, 0.f, 0.f}, acc1 = {0.f, 0.f, 0.f, 0.f};
#pragma unroll
    for (int ks = 0; ks < 4; ks++) {
        int k0 = ks * 32;
        half8 a  = *(half8*)&sH[c * 136 + k0 + q * 8];
        half8 b0 = *(const half8*)(WT + (size_t)(n0 + c) * 128 + k0 + q * 8);
        half8 b1 = *(const half8*)(WT + (size_t)(n0 + 16 + c) * 128 + k0 + q * 8);
        acc0 = __builtin_amdgcn_mfma_f32_16x16x32_f16(a, b0, acc0, 0, 0, 0);
        acc1 = __builtin_amdgcn_mfma_f32_16x16x32_f16(a, b1, acc1, 0, 0, 0);
    }
#pragma unroll
    for (int r = 0; r < 4; r++) {
        sO[(q * 4 + r) * 136 + n0 + c]      = (_Float16)acc0[r];
        sO[(q * 4 + r) * 136 + n0 + 16 + c] = (_Float16)acc1[r];
    }
    __syncthreads();
    if (row0 + lr < n)
        *(uint4*)(Gout + (size_t)(row0 + lr) * 128 + seg * 8) =
            *(uint4*)&sO[lr * 136 + seg * 8];
}

// segmented partial-sum: 4 waves/block, one wave per 32-node chunk
__global__ __launch_bounds__(256) void k_psum(
        const __half* __restrict__ h, const int* __restrict__ batch,
        float* __restrict__ sums, int n) {
    int lane = threadIdx.x & 63;
    int chunk = blockIdx.x * 4 + (threadIdx.x >> 6);
    int i0 = chunk * 32;
    if (i0 >= n) return;
    int iend = min(i0 + 32, n);
    const __half2* h2 = (const __half2*)h;
    float ax = 0.f, ay = 0.f;
    int curb = __builtin_amdgcn_readfirstlane(batch[i0]);
    for (int i = i0; i < iend; ++i) {
        int b = __builtin_amdgcn_readfirstlane(batch[i]);
        if (b != curb) {
            atomicAdd(&sums[(size_t)curb * 128 + 2 * lane], ax);
            atomicAdd(&sums[(size_t)curb * 128 + 2 * lane + 1], ay);
            ax = 0.f; ay = 0.f; curb = b;
        }
        float2 v = __half22float2(h2[(size_t)i * 64 + lane]);
        ax += v.x; ay += v.y;
    }
    atomicAdd(&sums[(size_t)curb * 128 + 2 * lane], ax);
    atomicAdd(&sums[(size_t)curb * 128 + 2 * lane + 1], ay);
}

// head: pooled = sums/cnt; out = pooled @ Wd2 + bd2. One block per graph.
__global__ __launch_bounds__(128) void k_head(
        const float* __restrict__ sums, const int* __restrict__ gs,
        const float* __restrict__ Wd2, const float* __restrict__ bd2,
        float* __restrict__ out) {
    int gidx = blockIdx.x;
    int j = threadIdx.x;
    int c = gs[gidx + 1] - gs[gidx];
    float inv = 1.0f / (float)(c > 1 ? c : 1);
    __shared__ float sp[128];
    sp[j] = sums[(size_t)gidx * 128 + j] * inv;
    __syncthreads();
    float o = bd2[j];
#pragma unroll 8
    for (int k = 0; k < 128; k++) o = fmaf(sp[k], Wd2[k * 128 + j], o);
    out[gidx * 128 + j] = o;
}

extern "C" void kernel_launch(void* const* d_in, const int* in_sizes, int n_in,
                              void* d_out, int out_size, void* d_ws, size_t ws_size,
                              hipStream_t stream) {
    const float* x   = (const float*)d_in[0];
    const int*  ei   = (const int*)d_in[1];
    const int* batch = (const int*)d_in[2];
    const float* Wd1 = (const float*)d_in[3];
    const float* bd1 = (const float*)d_in[4];
    const float* Wg1 = (const float*)d_in[5];
    const float* bg1 = (const float*)d_in[6];
    const float* Wg2 = (const float*)d_in[7];
    const float* bg2 = (const float*)d_in[8];
    const float* Wg3 = (const float*)d_in[9];
    const float* bg3 = (const float*)d_in[10];
    const float* Wd2 = (const float*)d_in[11];
    const float* bd2 = (const float*)d_in[12];
    float* out = (float*)d_out;

    int N  = in_sizes[0] / 4;       // N_FEAT = 4
    int E  = in_sizes[1] / 2;       // edge_index is [2, E]
    int NG = out_size / 128;        // 512 graphs
    const int* srcIdx = ei;
    const int* dstIdx = ei + E;
    int nbkt = (N + BSZ - 1) >> BSHIFT;     // 391 for N=100000

    char* p = (char*)d_ws;
    auto alloc = [&](size_t bytes) -> char* {
        char* r = p;
        p += (bytes + 255) & ~(size_t)255;
        return r;
    };
    int*    bktFill = (int*)alloc((size_t)nbkt * CPAD * 4);
    int*    staged  = (int*)alloc(((size_t)nbkt << CAPSH) * 4);   // 12.8 MB
    int*    col     = (int*)alloc(((size_t)nbkt << CAPSH) * 4);   // 12.8 MB
    int*    rpA     = (int*)alloc((size_t)N * 4);
    int*    reA     = (int*)alloc((size_t)N * 4);
    float*  dis     = (float*)alloc((size_t)N * 4);
    int*    gs      = (int*)alloc(((size_t)NG + 1) * 4);
    float*  sums    = (float*)alloc((size_t)NG * 128 * 4);
    __half* WT2     = (__half*)alloc(16384 * 2);
    __half* WT3     = (__half*)alloc(16384 * 2);
    __half* g       = (__half*)alloc((size_t)N * 128 * 2);
    __half* h       = (__half*)alloc((size_t)N * 128 * 2);
    (void)ws_size; (void)n_in;

    int L1B = (N + 1) / 2;                      // layer1 blocks
    int NB1 = (N + 255) / 256;                  // bounds blocks
    int ZW  = nbkt * CPAD + NG * 128;           // words to zero
    int ZB  = (ZW + 255) / 256;
    int prepB = L1B + 64 + NB1 + ZB;

    int eb4 = (E + 4095) / 4096;
    int ab  = (N + 3) / 4;
    int mmb = (N + 15) / 16;
    int pb  = (N + 127) / 128;

    k_prep<<<prepB, 256, 0, stream>>>(x, Wd1, bd1, Wg1, g, Wg2, Wg3, WT2, WT3,
                                      batch, gs, bktFill, sums, N, NG, nbkt,
                                      L1B, NB1);
    k_bin<<<eb4, 512, 0, stream>>>(srcIdx, dstIdx, bktFill, staged, E, nbkt);
    k_fineB<<<nbkt, 512, 0, stream>>>(staged, bktFill, rpA, reA, dis, col, N);

    k_agg<<<ab, 256, 0, stream>>>(g, rpA, reA, col, dis, bg1, h, N);
    k_mmMFMA<<<mmb, 256, 0, stream>>>(h, WT2, g, N);
    k_agg<<<ab, 256, 0, stream>>>(g, rpA, reA, col, dis, bg2, h, N);
    k_mmMFMA<<<mmb, 256, 0, stream>>>(h, WT3, g, N);
    k_agg<<<ab, 256, 0, stream>>>(g, rpA, reA, col, dis, bg3, h, N);

    k_psum<<<pb, 256, 0, stream>>>(h, batch, sums, N);
    k_head<<<NG, 128, 0, stream>>>(sums, gs, Wd2, bd2, out);
}

// Round 9
// 385.396 us; speedup vs baseline: 2.1440x; 1.1409x over previous
//
#include <hip/hip_runtime.h>
#include <hip/hip_fp16.h>

// ---------------------------------------------------------------------------
// FormulaNet GCN forward: 3x GCNConv(128) + mean-pool(512 graphs) + dense.
// R2: fp16 node tensors (fp32 math). R4: bucket-sort CSR. R5: psum+head.
// R6: MFMA mm, 256-node buckets. R7: prep mega-kernel, single-pass CSR.
// R8: deep fusion, 6 dispatches:
//     memset(bktFill) -> k_prep[bin|layer1|cvtW|bounds|zero-sums] -> k_fineB
//     -> k_aggmm(L1) -> k_aggmm(L2) -> k_aggsum(L3+pool) -> k_head.
//     agg edge loop unroll 4->8 (line-level parallelism: fp16 rows are 2
//     lines; R1's fp32 4-line rows sustained 3.4-4 TB/s on the L2-miss path
//     vs 2.8 now). rp/re -> int2 rpe (one s_load_dwordx2).
// ---------------------------------------------------------------------------

#define BSHIFT 8
#define BSZ    256          // nodes per bucket
#define MAXBKT 512          // LDS sizing bound (N <= 131072)
#define CPAD   32           // 1 counter / 128 B line for global cursors
#define CAPSH  13           // 8192 staged/col slots per bucket

typedef _Float16 half8 __attribute__((ext_vector_type(8)));
typedef float f32x4 __attribute__((ext_vector_type(4)));

// ---- prep: bin | layer1 | cvtW | bounds | zero(sums), by block range ----
__global__ __launch_bounds__(512) void k_prep(
        const float* __restrict__ x, const float* __restrict__ Wd1,
        const float* __restrict__ bd1, const float* __restrict__ Wg1,
        __half* __restrict__ g,
        const float* __restrict__ W2, const float* __restrict__ W3,
        __half* __restrict__ WT2, __half* __restrict__ WT3,
        const int* __restrict__ batch, int* __restrict__ gs,
        const int* __restrict__ src, const int* __restrict__ dst,
        int* __restrict__ bktFill, int* __restrict__ staged,
        float* __restrict__ sums,
        int N, int NG, int E, int nbkt, int BINB, int L1B, int NB1) {
    __shared__ float sW[512];
    __shared__ int hh[MAXBKT], base[MAXBKT], cur[MAXBKT];
    int bid = blockIdx.x;
    int t = threadIdx.x;
    if (bid < BINB) {
        // ---- bin: LDS hist -> one reservation/bucket -> staged scatter
        for (int i = t; i < nbkt; i += 512) { hh[i] = 0; cur[i] = 0; }
        __syncthreads();
        int e0 = bid * 4096 + t;
#pragma unroll
        for (int k = 0; k < 8; k++) {
            int e = e0 + k * 512;
            if (e < E) atomicAdd(&hh[dst[e] >> BSHIFT], 1);
        }
        __syncthreads();
        for (int i = t; i < nbkt; i += 512)
            base[i] = hh[i] ? atomicAdd(&bktFill[(size_t)i * CPAD], hh[i]) : 0;
        __syncthreads();
#pragma unroll
        for (int k = 0; k < 8; k++) {
            int e = e0 + k * 512;
            if (e < E) {
                int d = dst[e], s = src[e];
                int b = d >> BSHIFT;
                int off = atomicAdd(&cur[b], 1);
                staged[((size_t)b << CAPSH) + base[b] + off] =
                    ((d & (BSZ - 1)) << 17) | s;
            }
        }
    } else if (bid < BINB + L1B) {
        // ---- layer1: h0 = relu(x@Wd1+bd1); g = h0@Wg1 (fp16, bias deferred)
        int rb = bid - BINB;
        sW[t] = Wg1[t];
        __syncthreads();
        int j = t & 127;
        int node = rb * 4 + (t >> 7);
        if (node >= N) return;
        float4 xv = ((const float4*)x)[node];
        float acc = 0.f;
#pragma unroll
        for (int k = 0; k < 4; k++) {
            float h0 = xv.x * Wd1[k] + xv.y * Wd1[4 + k] + xv.z * Wd1[8 + k]
                     + xv.w * Wd1[12 + k] + bd1[k];
            h0 = fmaxf(h0, 0.f);
            acc = fmaf(h0, sW[k * 128 + j], acc);
        }
        g[(size_t)node * 128 + j] = __float2half_rn(acc);
    } else if (bid < BINB + L1B + 32) {
        // ---- cvtW: W fp32 [k][n] -> WT fp16 [n][k], both layers
        int t2 = (bid - BINB - L1B) * 512 + t;      // 0..16383
        int k = t2 >> 7, nn = t2 & 127;
        WT2[nn * 128 + k] = __float2half_rn(W2[t2]);
        WT3[nn * 128 + k] = __float2half_rn(W3[t2]);
    } else if (bid < BINB + L1B + 32 + NB1) {
        // ---- bounds: batch sorted -> per-graph node ranges
        int i = (bid - BINB - L1B - 32) * 512 + t;
        if (i >= N) return;
        int b = batch[i];
        int prev = (i == 0) ? -1 : batch[i - 1];
        for (int g2 = prev + 1; g2 <= b; ++g2) gs[g2] = i;
        if (i == N - 1)
            for (int g2 = b + 1; g2 <= NG; ++g2) gs[g2] = N;
    } else {
        // ---- zero sums
        int idx = (bid - BINB - L1B - 32 - NB1) * 512 + t;
        if (idx < NG * 128) sums[idx] = 0.f;
    }
}

// ---- per-bucket: hist -> deg/rpe/dis, LDS scan, window-local scatter ----
__global__ __launch_bounds__(512) void k_fineB(
        const int* __restrict__ staged, const int* __restrict__ bktFill,
        int2* __restrict__ rpe, float* __restrict__ dis,
        int* __restrict__ col, int N) {
    __shared__ int cnt[BSZ];
    __shared__ int incl[BSZ];
    int b = blockIdx.x;
    int lo = b << CAPSH;
    int cntE = bktFill[(size_t)b * CPAD];
    int n0 = b << BSHIFT;
    int tid = threadIdx.x;
    if (tid < BSZ) cnt[tid] = 0;
    __syncthreads();
    for (int e = tid; e < cntE; e += 512)
        atomicAdd(&cnt[staged[lo + e] >> 17], 1);
    __syncthreads();
    int v = 0;
    if (tid < BSZ) { v = cnt[tid]; incl[tid] = v; }
    for (int off = 1; off < BSZ; off <<= 1) {
        __syncthreads();
        int t = (tid < BSZ && tid >= off) ? incl[tid - off] : 0;
        __syncthreads();
        if (tid < BSZ) incl[tid] += t;
    }
    __syncthreads();
    int myofs = 0;
    if (tid < BSZ) {
        myofs = incl[tid] - v;                 // exclusive
        int node = n0 + tid;
        if (node < N) {
            rpe[node] = make_int2(lo + myofs, lo + myofs + v);
            dis[node] = rsqrtf((float)(v + 1));    // +1: self-loop
        }
    }
    __syncthreads();
    // reuse incl[] as base table, cnt[] as cursors
    if (tid < BSZ) { incl[tid] = myofs; cnt[tid] = 0; }
    __syncthreads();
    for (int e = tid; e < cntE; e += 512) {
        int ent = staged[lo + e];
        int dl = ent >> 17;
        int pos = lo + incl[dl] + atomicAdd(&cnt[dl], 1);
        col[pos] = ent & 0x1FFFF;
    }
}

// per-node aggregation (64-lane wave, lane = feats {2l,2l+1}); unroll 8
__device__ __forceinline__ float2 agg_node(
        const __half2* __restrict__ g2, const int* __restrict__ col,
        const float* __restrict__ dis, int r0, int r1, int node,
        float di, int lane) {
    float2 me = __half22float2(g2[(size_t)node * 64 + lane]);
    float ax = di * me.x, ay = di * me.y;       // self-loop (dis_i factored out)
    int e = r0;
    for (; e + 7 < r1; e += 8) {
        int s0 = __builtin_amdgcn_readfirstlane(col[e]);
        int s1 = __builtin_amdgcn_readfirstlane(col[e + 1]);
        int s2 = __builtin_amdgcn_readfirstlane(col[e + 2]);
        int s3 = __builtin_amdgcn_readfirstlane(col[e + 3]);
        int s4 = __builtin_amdgcn_readfirstlane(col[e + 4]);
        int s5 = __builtin_amdgcn_readfirstlane(col[e + 5]);
        int s6 = __builtin_amdgcn_readfirstlane(col[e + 6]);
        int s7 = __builtin_amdgcn_readfirstlane(col[e + 7]);
        float w0 = dis[s0], w1 = dis[s1], w2 = dis[s2], w3 = dis[s3];
        float w4 = dis[s4], w5 = dis[s5], w6 = dis[s6], w7 = dis[s7];
        float2 v0 = __half22float2(g2[(size_t)s0 * 64 + lane]);
        float2 v1 = __half22float2(g2[(size_t)s1 * 64 + lane]);
        float2 v2 = __half22float2(g2[(size_t)s2 * 64 + lane]);
        float2 v3 = __half22float2(g2[(size_t)s3 * 64 + lane]);
        float2 v4 = __half22float2(g2[(size_t)s4 * 64 + lane]);
        float2 v5 = __half22float2(g2[(size_t)s5 * 64 + lane]);
        float2 v6 = __half22float2(g2[(size_t)s6 * 64 + lane]);
        float2 v7 = __half22float2(g2[(size_t)s7 * 64 + lane]);
        ax = fmaf(w0, v0.x, ax); ay = fmaf(w0, v0.y, ay);
        ax = fmaf(w1, v1.x, ax); ay = fmaf(w1, v1.y, ay);
        ax = fmaf(w2, v2.x, ax); ay = fmaf(w2, v2.y, ay);
        ax = fmaf(w3, v3.x, ax); ay = fmaf(w3, v3.y, ay);
        ax = fmaf(w4, v4.x, ax); ay = fmaf(w4, v4.y, ay);
        ax = fmaf(w5, v5.x, ax); ay = fmaf(w5, v5.y, ay);
        ax = fmaf(w6, v6.x, ax); ay = fmaf(w6, v6.y, ay);
        ax = fmaf(w7, v7.x, ax); ay = fmaf(w7, v7.y, ay);
    }
    for (; e < r1; ++e) {
        int s0 = __builtin_amdgcn_readfirstlane(col[e]);
        float w0 = dis[s0];
        float2 v0 = __half22float2(g2[(size_t)s0 * 64 + lane]);
        ax = fmaf(w0, v0.x, ax); ay = fmaf(w0, v0.y, ay);
    }
    return make_float2(ax, ay);
}

// fused GCN layer: block = 16 nodes (4 waves x 4 serial nodes).
// agg (+bias,relu) -> LDS rows -> mfma_f32_16x16x32_f16 -> gout (no bias).
__global__ __launch_bounds__(256) void k_aggmm(
        const __half* __restrict__ gin, const int2* __restrict__ rpe,
        const int* __restrict__ col, const float* __restrict__ dis,
        const float* __restrict__ bias, const __half* __restrict__ WT,
        __half* __restrict__ gout, int n) {
    __shared__ _Float16 sH[16 * 136];
    __shared__ _Float16 sO[16 * 136];
    int t = threadIdx.x;
    int wave = t >> 6, lane = t & 63;
    const __half2* g2 = (const __half2*)gin;
    float2 bb = ((const float2*)bias)[lane];
#pragma unroll
    for (int i = 0; i < 4; i++) {
        int node = __builtin_amdgcn_readfirstlane(blockIdx.x * 16 + wave * 4 + i);
        if (node < n) {
            int2 re = rpe[node];
            int r0 = __builtin_amdgcn_readfirstlane(re.x);
            int r1 = __builtin_amdgcn_readfirstlane(re.y);
            float di = dis[node];
            float2 a = agg_node(g2, col, dis, r0, r1, node, di, lane);
            float ox = fmaxf(fmaf(di, a.x, bb.x), 0.f);
            float oy = fmaxf(fmaf(di, a.y, bb.y), 0.f);
            int lr = wave * 4 + i;
            sH[lr * 136 + 2 * lane]     = (_Float16)ox;
            sH[lr * 136 + 2 * lane + 1] = (_Float16)oy;
        }
    }
    __syncthreads();
    // mm: wave covers cols [wave*32, wave*32+32) for all 16 rows
    int q = lane >> 4, c = lane & 15;
    int n0 = wave * 32;
    f32x4 acc0 = {0.f, 0.f, 0.f, 0.f}, acc1 = {0.f, 0.f, 0.f, 0.f};
#pragma unroll
    for (int ks = 0; ks < 4; ks++) {
        int k0 = ks * 32;
        half8 a  = *(half8*)&sH[c * 136 + k0 + q * 8];
        half8 b0 = *(const half8*)(WT + (size_t)(n0 + c) * 128 + k0 + q * 8);
        half8 b1 = *(const half8*)(WT + (size_t)(n0 + 16 + c) * 128 + k0 + q * 8);
        acc0 = __builtin_amdgcn_mfma_f32_16x16x32_f16(a, b0, acc0, 0, 0, 0);
        acc1 = __builtin_amdgcn_mfma_f32_16x16x32_f16(a, b1, acc1, 0, 0, 0);
    }
#pragma unroll
    for (int r = 0; r < 4; r++) {
        sO[(q * 4 + r) * 136 + n0 + c]      = (_Float16)acc0[r];
        sO[(q * 4 + r) * 136 + n0 + 16 + c] = (_Float16)acc1[r];
    }
    __syncthreads();
    int lr2 = t >> 4, seg = t & 15;
    int row = blockIdx.x * 16 + lr2;
    if (row < n)
        *(uint4*)(gout + (size_t)row * 128 + seg * 8) =
            *(uint4*)&sO[lr2 * 136 + seg * 8];
}

// fused layer-3 agg + mean-pool partial sums (batch sorted; segmented
// register accumulation over each wave's 4 nodes, flush on graph change)
__global__ __launch_bounds__(256) void k_aggsum(
        const __half* __restrict__ gin, const int2* __restrict__ rpe,
        const int* __restrict__ col, const float* __restrict__ dis,
        const float* __restrict__ bias, const int* __restrict__ batch,
        float* __restrict__ sums, int n) {
    int t = threadIdx.x;
    int wave = t >> 6, lane = t & 63;
    const __half2* g2 = (const __half2*)gin;
    float2 bb = ((const float2*)bias)[lane];
    float sx = 0.f, sy = 0.f;
    int curb = -1;
#pragma unroll
    for (int i = 0; i < 4; i++) {
        int node = __builtin_amdgcn_readfirstlane(blockIdx.x * 16 + wave * 4 + i);
        if (node < n) {
            int2 re = rpe[node];
            int r0 = __builtin_amdgcn_readfirstlane(re.x);
            int r1 = __builtin_amdgcn_readfirstlane(re.y);
            float di = dis[node];
            float2 a = agg_node(g2, col, dis, r0, r1, node, di, lane);
            float ox = fmaxf(fmaf(di, a.x, bb.x), 0.f);
            float oy = fmaxf(fmaf(di, a.y, bb.y), 0.f);
            int b = __builtin_amdgcn_readfirstlane(batch[node]);
            if (b != curb) {
                if (curb >= 0) {
                    atomicAdd(&sums[(size_t)curb * 128 + 2 * lane], sx);
                    atomicAdd(&sums[(size_t)curb * 128 + 2 * lane + 1], sy);
                }
                sx = 0.f; sy = 0.f; curb = b;
            }
            sx += ox; sy += oy;
        }
    }
    if (curb >= 0) {
        atomicAdd(&sums[(size_t)curb * 128 + 2 * lane], sx);
        atomicAdd(&sums[(size_t)curb * 128 + 2 * lane + 1], sy);
    }
}

// head: pooled = sums/cnt; out = pooled @ Wd2 + bd2. One block per graph.
__global__ __launch_bounds__(128) void k_head(
        const float* __restrict__ sums, const int* __restrict__ gs,
        const float* __restrict__ Wd2, const float* __restrict__ bd2,
        float* __restrict__ out) {
    int gidx = blockIdx.x;
    int j = threadIdx.x;
    int c = gs[gidx + 1] - gs[gidx];
    float inv = 1.0f / (float)(c > 1 ? c : 1);
    __shared__ float sp[128];
    sp[j] = sums[(size_t)gidx * 128 + j] * inv;
    __syncthreads();
    float o = bd2[j];
#pragma unroll 8
    for (int k = 0; k < 128; k++) o = fmaf(sp[k], Wd2[k * 128 + j], o);
    out[gidx * 128 + j] = o;
}

extern "C" void kernel_launch(void* const* d_in, const int* in_sizes, int n_in,
                              void* d_out, int out_size, void* d_ws, size_t ws_size,
                              hipStream_t stream) {
    const float* x   = (const float*)d_in[0];
    const int*  ei   = (const int*)d_in[1];
    const int* batch = (const int*)d_in[2];
    const float* Wd1 = (const float*)d_in[3];
    const float* bd1 = (const float*)d_in[4];
    const float* Wg1 = (const float*)d_in[5];
    const float* bg1 = (const float*)d_in[6];
    const float* Wg2 = (const float*)d_in[7];
    const float* bg2 = (const float*)d_in[8];
    const float* Wg3 = (const float*)d_in[9];
    const float* bg3 = (const float*)d_in[10];
    const float* Wd2 = (const float*)d_in[11];
    const float* bd2 = (const float*)d_in[12];
    float* out = (float*)d_out;

    int N  = in_sizes[0] / 4;       // N_FEAT = 4
    int E  = in_sizes[1] / 2;       // edge_index is [2, E]
    int NG = out_size / 128;        // 512 graphs
    const int* srcIdx = ei;
    const int* dstIdx = ei + E;
    int nbkt = (N + BSZ - 1) >> BSHIFT;     // 391 for N=100000

    char* p = (char*)d_ws;
    auto alloc = [&](size_t bytes) -> char* {
        char* r = p;
        p += (bytes + 255) & ~(size_t)255;
        return r;
    };
    int*    bktFill = (int*)alloc((size_t)nbkt * CPAD * 4);
    int*    staged  = (int*)alloc(((size_t)nbkt << CAPSH) * 4);   // 12.8 MB
    int*    col     = (int*)alloc(((size_t)nbkt << CAPSH) * 4);   // 12.8 MB
    int2*   rpe     = (int2*)alloc((size_t)N * 8);
    float*  dis     = (float*)alloc((size_t)N * 4);
    int*    gs      = (int*)alloc(((size_t)NG + 1) * 4);
    float*  sums    = (float*)alloc((size_t)NG * 128 * 4);
    __half* WT2     = (__half*)alloc(16384 * 2);
    __half* WT3     = (__half*)alloc(16384 * 2);
    __half* gA      = (__half*)alloc((size_t)N * 128 * 2);
    __half* gB      = (__half*)alloc((size_t)N * 128 * 2);
    (void)ws_size; (void)n_in;

    int BINB = (E + 4095) / 4096;               // 391
    int L1B  = (N + 3) / 4;                     // 25000
    int NB1  = (N + 511) / 512;                 // 196
    int ZB   = (NG * 128 + 511) / 512;          // 128
    int prepB = BINB + L1B + 32 + NB1 + ZB;
    int fb   = (N + 15) / 16;                   // 6250

    hipMemsetAsync(bktFill, 0, (size_t)nbkt * CPAD * 4, stream);  // 50 KB

    k_prep<<<prepB, 512, 0, stream>>>(x, Wd1, bd1, Wg1, gA, Wg2, Wg3, WT2, WT3,
                                      batch, gs, srcIdx, dstIdx, bktFill,
                                      staged, sums, N, NG, E, nbkt,
                                      BINB, L1B, NB1);
    k_fineB<<<nbkt, 512, 0, stream>>>(staged, bktFill, rpe, dis, col, N);

    k_aggmm<<<fb, 256, 0, stream>>>(gA, rpe, col, dis, bg1, WT2, gB, N);
    k_aggmm<<<fb, 256, 0, stream>>>(gB, rpe, col, dis, bg2, WT3, gA, N);
    k_aggsum<<<fb, 256, 0, stream>>>(gA, rpe, col, dis, bg3, batch, sums, N);

    k_head<<<NG, 128, 0, stream>>>(sums, gs, Wd2, bd2, out);
}